// Round 4
// baseline (311.987 us; speedup 1.0000x reference)
//
#include <hip/hip_runtime.h>
#include <hip/hip_bf16.h>
#include <math.h>

typedef __bf16 bf16;
typedef __bf16 bf16x4 __attribute__((ext_vector_type(4)));
typedef __bf16 bf16x8 __attribute__((ext_vector_type(8)));
typedef float f32x4 __attribute__((ext_vector_type(4)));

#define DIM 768
#define HID 3072
#define HID2 1536
#define NLEV 9
#define SEQ 2048
#define ROWS 4096            // BATCH*SEQ
#define MAXPAD2 6400         // ROWS + NLEV*256 (256-row gather tiles)
#define MAXT2 25             // MAXPAD2/256

// ---------------- async global->LDS 16B ----------------
__device__ __forceinline__ void gld16(const void* g, void* l) {
    __builtin_amdgcn_global_load_lds(
        (const __attribute__((address_space(1))) void*)g,
        (__attribute__((address_space(3))) void*)l, 16, 0, 0);
}

// fast tanh-GELU: max |err| vs exact-erf gelu ~5e-4
__device__ __forceinline__ float fast_gelu(float v) {
    float v2 = v * v;
    float twou = v * (1.59576912f + 0.071354816f * v2);
    float t = __expf(twou);
    return v * t / (t + 1.0f);
}

// T1: XCD-bijective swizzle (m204)
__device__ __forceinline__ int xcd_swizzle(int s, int nwg) {
    int q = nwg >> 3, r = nwg & 7;
    int x = s & 7, i = s >> 3;
    return (x < r ? x * (q + 1) : r * (q + 1) + (x - r) * q) + i;
}

// ================= PREP bodies =================

// LayerNorm, one WAVE per row. Block = 4 waves = 4 rows.
__device__ __forceinline__ void ln4_body(int blk,
                                         const float* __restrict__ x,
                                         const float* __restrict__ gamma,
                                         const float* __restrict__ beta,
                                         bf16* __restrict__ xn) {
    int tid = threadIdx.x;
    int wv = tid >> 6, ln = tid & 63;
    int row = blk * 4 + wv;
    const float* xr = x + (size_t)row * DIM;
    int c = ln * 4;
    float4 v0 = *(const float4*)(xr + c);
    float4 v1 = *(const float4*)(xr + c + 256);
    float4 v2 = *(const float4*)(xr + c + 512);
    float s = v0.x + v0.y + v0.z + v0.w
            + v1.x + v1.y + v1.z + v1.w
            + v2.x + v2.y + v2.z + v2.w;
    float q = v0.x * v0.x + v0.y * v0.y + v0.z * v0.z + v0.w * v0.w
            + v1.x * v1.x + v1.y * v1.y + v1.z * v1.z + v1.w * v1.w
            + v2.x * v2.x + v2.y * v2.y + v2.z * v2.z + v2.w * v2.w;
#pragma unroll
    for (int off = 32; off; off >>= 1) {
        s += __shfl_xor(s, off, 64);
        q += __shfl_xor(q, off, 64);
    }
    float m = s * (1.0f / DIM);
    float r = rsqrtf(q * (1.0f / DIM) - m * m + 1e-5f);
    bf16* xo = xn + (size_t)row * DIM;
#pragma unroll
    for (int p = 0; p < 3; p++) {
        int cc = c + p * 256;
        float4 v = (p == 0) ? v0 : (p == 1) ? v1 : v2;
        float4 g = *(const float4*)(gamma + cc);
        float4 b = *(const float4*)(beta + cc);
        bf16x4 o;
        o[0] = (bf16)((v.x - m) * r * g.x + b.x);
        o[1] = (bf16)((v.y - m) * r * g.y + b.y);
        o[2] = (bf16)((v.z - m) * r * g.z + b.z);
        o[3] = (bf16)((v.w - m) * r * g.w + b.w);
        *(bf16x4*)(xo + cc) = o;
    }
}

// 64x64 tile transpose: fp32 [R][C] -> bf16 [C][R]. bf16 LDS [64][68] (8.4 KB).
__device__ __forceinline__ void transpose_body64(bf16* sm,
                                                 const float* __restrict__ inb,
                                                 bf16* __restrict__ outb,
                                                 int R, int C, int bx, int by) {
    int tid = threadIdx.x;
    int ty = tid >> 4;
    int tx4 = (tid & 15) * 4;
#pragma unroll
    for (int p = 0; p < 4; p++) {
        int rloc = p * 16 + ty;
        int row = by * 64 + rloc;
        float4 v = *(const float4*)(inb + (size_t)row * C + bx * 64 + tx4);
        bf16x4 o;
        o[0] = (bf16)v.x; o[1] = (bf16)v.y; o[2] = (bf16)v.z; o[3] = (bf16)v.w;
        *(bf16x4*)(sm + rloc * 68 + tx4) = o;
    }
    __syncthreads();
    int ch = tid & 7;
    int ocb = tid >> 3;
#pragma unroll
    for (int p = 0; p < 2; p++) {
        int oc = p * 32 + ocb;
        bf16x8 tmp;
#pragma unroll
        for (int k = 0; k < 8; k++) tmp[k] = sm[(ch * 8 + k) * 68 + oc];
        *(bf16x8*)(outb + (size_t)(bx * 64 + oc) * R + by * 64 + ch * 8) = tmp;
    }
}

__device__ __forceinline__ void routing_body(float* sm,
                                             const int* __restrict__ levels_info,
                                             const float* __restrict__ lmw,
                                             float* __restrict__ mix,
                                             int* __restrict__ row_index,
                                             int* __restrict__ tile_meta,
                                             float* __restrict__ zbuf) {
    int* cnt = (int*)sm;
    int* cur = cnt + NLEV;
    int* off = cur + NLEV;
    float* mixv = (float*)(off + NLEV);
    int tid = threadIdx.x;
    if (tid < NLEV) { cnt[tid] = 0; cur[tid] = 0; }
    __syncthreads();
    for (int s = tid; s < SEQ; s += 256) {
        int d = levels_info[s * 4];
        d = d < 0 ? 0 : (d > 8 ? 8 : d);
        atomicAdd(&cnt[d], 1);
    }
    for (int i = tid; i < MAXPAD2; i += 256) row_index[i] = -1;
    for (int i = tid; i < 1024; i += 256) zbuf[i] = 0.0f;   // 4 KB zero page
    __syncthreads();
    if (tid == 0) {
        float mx = lmw[0];
        for (int l = 1; l < NLEV; l++) mx = fmaxf(mx, lmw[l]);
        float denom = 0.f;
        for (int l = 0; l < NLEV; l++) denom += (float)cnt[l] * expf(lmw[l] - mx);
        float inv = 1.0f / denom;
        int running = 0, t = 0;
        for (int l = 0; l < NLEV; l++) {
            mixv[l] = expf(lmw[l] - mx) * inv;
            off[l] = running;
            int seg = (2 * cnt[l] + 255) & ~255;       // 256-row tiles
            for (int k = 0; k < seg / 256; k++) tile_meta[t++] = l;
            running += seg;
        }
        for (; t < MAXT2; t++) tile_meta[t] = -1;
    }
    __syncthreads();
    for (int s = tid; s < SEQ; s += 256) {
        int d = levels_info[s * 4];
        d = d < 0 ? 0 : (d > 8 ? 8 : d);
        int p = atomicAdd(&cur[d], 2);
        row_index[off[d] + p]     = s;
        row_index[off[d] + p + 1] = s + SEQ;
        mix[s] = mixv[d];
    }
}

// ---------------- prep: routing + LN + ALL weight transposes ----------------
__global__ __launch_bounds__(256) void prep_kernel(const float* __restrict__ x,
                                                   const int* __restrict__ levels_info,
                                                   const float* __restrict__ gamma,
                                                   const float* __restrict__ beta,
                                                   const float* __restrict__ W1,
                                                   const float* __restrict__ A1,
                                                   const float* __restrict__ W2,
                                                   const float* __restrict__ A2,
                                                   const float* __restrict__ lmw,
                                                   bf16* __restrict__ Xn,
                                                   bf16* __restrict__ W1t,
                                                   bf16* __restrict__ A1t,
                                                   bf16* __restrict__ W2t,
                                                   bf16* __restrict__ A2t,
                                                   float* __restrict__ mix,
                                                   int* __restrict__ row_index,
                                                   int* __restrict__ tile_meta,
                                                   float* __restrict__ zbuf) {
    __shared__ __align__(16) bf16 tsm[64 * 68];
    int b = blockIdx.x;
    if (b == 0) { routing_body((float*)tsm, levels_info, lmw, mix, row_index, tile_meta, zbuf); return; }
    b -= 1;
    if (b < 1024) { ln4_body(b, x, gamma, beta, Xn); return; }
    b -= 1024;
    if (b < 576) {
        transpose_body64(tsm, W1, W1t, DIM, HID, b % 48, b / 48);
        return;
    }
    b -= 576;
    if (b < 2592) {
        int bz = b / 288, r = b % 288;
        transpose_body64(tsm, A1 + (size_t)bz * DIM * HID2, A1t + (size_t)bz * DIM * HID2,
                         DIM, HID2, r % 24, r / 24);
        return;
    }
    b -= 2592;
    if (b < 576) {
        transpose_body64(tsm, W2, W2t, HID, DIM, b % 12, b / 12);
        return;
    }
    b -= 576;
    {
        int bz = b / 288, r = b % 288;
        transpose_body64(tsm, A2 + (size_t)bz * HID2 * DIM, A2t + (size_t)bz * HID2 * DIM,
                         HID2, DIM, r % 12, r / 12);
    }
}

// ============ 256x256 8-wave 4-phase GEMM core (BK=64) ============
// 512 threads = 8 waves (2 wm x 4 wn); wave output 128x64 = acc[8][4].
// LDS (dynamic, 128 KB): As dbuf [2][256][64], Bs dbuf [2][256][64].
// Staging: gld16 linear dest; source pre-swizzled chunk = (lane&7)^(lane>>3).
// Schedule per K-step: 4 phases; stage split 4+4 over phases 0/1 so phase-0's
// vmcnt(0) drain targets loads >=2 phase-walls old (latency hidden).
#define SBUF 16384          // elems per stage buffer

template<int KT>
__device__ __forceinline__ void gemm_loop_8w(const bf16* (&ga)[4], const bf16* (&gb)[4],
                                             bf16* smem, f32x4 (&acc)[8][4]) {
    const int tid = threadIdx.x;
    const int wv = tid >> 6, lane = tid & 63;
    const int wm = wv >> 2, wn = wv & 3;
    const int r = lane & 15;
    const int ch0 = ((lane >> 4) ^ (lane & 7)) * 8;
    const int aoff = (wm * 128 + r) * 64 + ch0;
    const int boff = (wn * 64 + r) * 64 + ch0;
    bf16* As = smem;
    bf16* Bs = smem + 2 * SBUF;
    const int sA = wv * 512;                    // wave stage base (8 rows x 64)
    // prologue: stage step-0 into buf0
#pragma unroll
    for (int c = 0; c < 4; c++) {
        gld16(ga[c], As + sA + c * 4096);
        gld16(gb[c], Bs + sA + c * 4096);
        ga[c] += 64; gb[c] += 64;
    }
#pragma unroll 2
    for (int kt = 0; kt < KT; ++kt) {
        const int cur = (kt & 1) ? SBUF : 0;
        const int nxt = cur ^ SBUF;
        const bf16* Ac = As + cur;
        const bf16* Bc = Bs + cur;
        bf16x8 a[4], b[4];
        // ---------------- phase 0 ----------------
        asm volatile("s_waitcnt vmcnt(0)" ::: "memory");
        __builtin_amdgcn_s_barrier();
        __builtin_amdgcn_sched_barrier(0);
        if (kt + 1 < KT) {
            gld16(ga[0], As + nxt + sA);
            gld16(gb[0], Bs + nxt + sA);
            gld16(ga[1], As + nxt + sA + 4096);
            gld16(gb[1], Bs + nxt + sA + 4096);
            ga[0] += 64; gb[0] += 64; ga[1] += 64; gb[1] += 64;
        }
#pragma unroll
        for (int i = 0; i < 4; i++) a[i] = *(const bf16x8*)(Ac + aoff + i * 1024);
#pragma unroll
        for (int j = 0; j < 4; j++) b[j] = *(const bf16x8*)(Bc + boff + j * 1024);
        __builtin_amdgcn_s_setprio(1);
#pragma unroll
        for (int i = 0; i < 4; i++)
#pragma unroll
            for (int j = 0; j < 4; j++)
                acc[i][j] = __builtin_amdgcn_mfma_f32_16x16x32_bf16(a[i], b[j], acc[i][j], 0, 0, 0);
        __builtin_amdgcn_s_setprio(0);
        __builtin_amdgcn_s_barrier();
        // ---------------- phase 1 ----------------
        if (kt + 1 < KT) {
            gld16(ga[2], As + nxt + sA + 8192);
            gld16(gb[2], Bs + nxt + sA + 8192);
            gld16(ga[3], As + nxt + sA + 12288);
            gld16(gb[3], Bs + nxt + sA + 12288);
            ga[2] += 64; gb[2] += 64; ga[3] += 64; gb[3] += 64;
        }
#pragma unroll
        for (int i = 0; i < 4; i++) a[i] = *(const bf16x8*)(Ac + aoff + (4 + i) * 1024);
        __builtin_amdgcn_s_setprio(1);
#pragma unroll
        for (int i = 0; i < 4; i++)
#pragma unroll
            for (int j = 0; j < 4; j++)
                acc[4 + i][j] = __builtin_amdgcn_mfma_f32_16x16x32_bf16(a[i], b[j], acc[4 + i][j], 0, 0, 0);
        __builtin_amdgcn_s_setprio(0);
        __builtin_amdgcn_s_barrier();
        // ---------------- phase 2 (k32=1) ----------------
#pragma unroll
        for (int i = 0; i < 4; i++) a[i] = *(const bf16x8*)(Ac + ((aoff + i * 1024) ^ 32));
#pragma unroll
        for (int j = 0; j < 4; j++) b[j] = *(const bf16x8*)(Bc + ((boff + j * 1024) ^ 32));
        __builtin_amdgcn_s_setprio(1);
#pragma unroll
        for (int i = 0; i < 4; i++)
#pragma unroll
            for (int j = 0; j < 4; j++)
                acc[i][j] = __builtin_amdgcn_mfma_f32_16x16x32_bf16(a[i], b[j], acc[i][j], 0, 0, 0);
        __builtin_amdgcn_s_setprio(0);
        __builtin_amdgcn_s_barrier();
        // ---------------- phase 3 ----------------
#pragma unroll
        for (int i = 0; i < 4; i++) a[i] = *(const bf16x8*)(Ac + ((aoff + (4 + i) * 1024) ^ 32));
        __builtin_amdgcn_s_setprio(1);
#pragma unroll
        for (int i = 0; i < 4; i++)
#pragma unroll
            for (int j = 0; j < 4; j++)
                acc[4 + i][j] = __builtin_amdgcn_mfma_f32_16x16x32_bf16(a[i], b[j], acc[4 + i][j], 0, 0, 0);
        __builtin_amdgcn_s_setprio(0);
        // no trailing barrier: next phase-0 opens with vmcnt+barrier
    }
}

#define ACC_INIT8(acc) \
    _Pragma("unroll") for (int i = 0; i < 8; i++) \
    _Pragma("unroll") for (int j = 0; j < 4; j++) acc[i][j] = (f32x4){0.f, 0.f, 0.f, 0.f};

// ---------------- mlp1: gemm1(192) + agemm1(150), 256^2 tiles ----------------
__global__ __launch_bounds__(512) void mlp1_kernel(const bf16* __restrict__ Xn,
                                                   const bf16* __restrict__ W1t,
                                                   const float* __restrict__ b1,
                                                   bf16* __restrict__ H,
                                                   const bf16* __restrict__ A1t,
                                                   const float* __restrict__ a1b,
                                                   const int* __restrict__ row_index,
                                                   const int* __restrict__ tile_meta,
                                                   const bf16* __restrict__ zbuf,
                                                   bf16* __restrict__ HL) {
    extern __shared__ __align__(16) bf16 smem[];   // 128 KB
    int bid = xcd_swizzle(blockIdx.x, 342);
    int tid = threadIdx.x;
    int wv = tid >> 6, lane = tid & 63;
    int wm = wv >> 2, wn = wv & 3;
    int srow = lane >> 3;                      // 0..7 within 8-row stage group
    int lch = ((lane & 7) ^ srow) * 8;         // pre-swizzled global chunk
    f32x4 acc[8][4];
    ACC_INIT8(acc);
    bf16* cbuf = smem + wv * 8192;             // epilogue: wave-private 128x64

    if (bid < 192) {
        // ---- gemm1: M=4096(16 mb) x N=3072(12 nb), K=768 ----
        int nb = bid % 12, mb = bid / 12;
        const bf16* ga[4]; const bf16* gb[4];
#pragma unroll
        for (int c = 0; c < 4; c++) {
            int rt = c * 64 + wv * 8 + srow;
            ga[c] = Xn  + (size_t)(mb * 256 + rt) * DIM + lch;
            gb[c] = W1t + (size_t)(nb * 256 + rt) * DIM + lch;
        }
        gemm_loop_8w<12>(ga, gb, smem, acc);
        __syncthreads();
        int cbase = nb * 256 + wn * 64 + (lane & 15);
#pragma unroll
        for (int j = 0; j < 4; j++) {
            float bias = b1[cbase + j * 16];
#pragma unroll
            for (int i = 0; i < 8; i++)
#pragma unroll
                for (int rr = 0; rr < 4; rr++) {
                    int lr = i * 16 + ((lane >> 4) << 2) + rr;
                    cbuf[lr * 64 + j * 16 + (lane & 15)] = (bf16)fast_gelu(acc[i][j][rr] + bias);
                }
        }
        bf16* gp = H + (size_t)(mb * 256 + wm * 128) * HID + nb * 256 + wn * 64;
#pragma unroll
        for (int p = 0; p < 16; p++) {
            int lr = p * 8 + srow;
            int chunk = (lane & 7) * 8;
            *(bf16x8*)(gp + (size_t)lr * HID + chunk) = *(const bf16x8*)(cbuf + lr * 64 + chunk);
        }
    } else {
        // ---- agemm1: 25 tiles (256-row gather) x 6 nb(256 of 1536) ----
        int t2 = bid - 192;
        int nb = t2 % 6, t = t2 / 6;
        int lvl = tile_meta[t];
        if (lvl < 0) return;
        const bf16* ga[4]; const bf16* gb[4];
        const bf16* Bl = A1t + (size_t)lvl * HID2 * DIM;
#pragma unroll
        for (int c = 0; c < 4; c++) {
            int rt = c * 64 + wv * 8 + srow;
            int rg = row_index[t * 256 + rt];
            ga[c] = (rg >= 0) ? (Xn + (size_t)rg * DIM + lch) : (zbuf + lch);
            gb[c] = Bl + (size_t)(nb * 256 + rt) * DIM + lch;
        }
        gemm_loop_8w<12>(ga, gb, smem, acc);
        __syncthreads();
        int cbase = nb * 256 + wn * 64 + (lane & 15);
#pragma unroll
        for (int j = 0; j < 4; j++) {
            float bias = a1b[lvl * HID2 + cbase + j * 16];
#pragma unroll
            for (int i = 0; i < 8; i++)
#pragma unroll
                for (int rr = 0; rr < 4; rr++) {
                    int lr = i * 16 + ((lane >> 4) << 2) + rr;
                    cbuf[lr * 64 + j * 16 + (lane & 15)] = (bf16)fmaxf(acc[i][j][rr] + bias, 0.0f);
                }
        }
        bf16* gp = HL + (size_t)(t * 256 + wm * 128) * HID2 + nb * 256 + wn * 64;
#pragma unroll
        for (int p = 0; p < 16; p++) {
            int lr = p * 8 + srow;
            int chunk = (lane & 7) * 8;
            *(bf16x8*)(gp + (size_t)lr * HID2 + chunk) = *(const bf16x8*)(cbuf + lr * 64 + chunk);
        }
    }
}

// ---------------- mlp2: agemm2(150, KT=24, dispatched first) + gemm2 splitK4(192, KT=12) ----------------
__global__ __launch_bounds__(512) void mlp2_kernel(const bf16* __restrict__ H,
                                                   const bf16* __restrict__ W2t,
                                                   bf16* __restrict__ part,   // [4][ROWS*DIM]
                                                   const bf16* __restrict__ HL,
                                                   const bf16* __restrict__ A2t,
                                                   const float* __restrict__ a2b,
                                                   const int* __restrict__ row_index,
                                                   const int* __restrict__ tile_meta,
                                                   bf16* __restrict__ apart) { // [ROWS*DIM]
    extern __shared__ __align__(16) bf16 smem[];   // 128 KB
    int bid = xcd_swizzle(blockIdx.x, 342);
    int tid = threadIdx.x;
    int wv = tid >> 6, lane = tid & 63;
    int wm = wv >> 2, wn = wv & 3;
    int srow = lane >> 3;
    int lch = ((lane & 7) ^ srow) * 8;
    f32x4 acc[8][4];
    ACC_INIT8(acc);
    bf16* cbuf = smem + wv * 8192;

    if (bid < 150) {
        // ---- agemm2: 25 tiles x 3 nb(256 of 768), full K=1536 (long blocks first) ----
        int nb = bid % 3, t = bid / 3;
        int lvl = tile_meta[t];
        if (lvl < 0) return;
        const bf16* ga[4]; const bf16* gb[4];
        const bf16* Bl = A2t + (size_t)lvl * DIM * HID2;
#pragma unroll
        for (int c = 0; c < 4; c++) {
            int rt = c * 64 + wv * 8 + srow;
            ga[c] = HL + (size_t)(t * 256 + rt) * HID2 + lch;
            gb[c] = Bl + (size_t)(nb * 256 + rt) * HID2 + lch;
        }
        gemm_loop_8w<24>(ga, gb, smem, acc);
        __syncthreads();
        int cbase = nb * 256 + wn * 64 + (lane & 15);
#pragma unroll
        for (int j = 0; j < 4; j++) {
            float bias = a2b[lvl * DIM + cbase + j * 16];
#pragma unroll
            for (int i = 0; i < 8; i++)
#pragma unroll
                for (int rr = 0; rr < 4; rr++) {
                    int lr = i * 16 + ((lane >> 4) << 2) + rr;
                    cbuf[lr * 64 + j * 16 + (lane & 15)] = (bf16)(acc[i][j][rr] + bias);
                }
        }
        int colg = nb * 256 + wn * 64;
#pragma unroll
        for (int p = 0; p < 16; p++) {
            int lr = p * 8 + srow;
            int chunk = (lane & 7) * 8;
            int rg = row_index[t * 256 + wm * 128 + lr];
            if (rg >= 0) {
                *(bf16x8*)(apart + (size_t)rg * DIM + colg + chunk) =
                    *(const bf16x8*)(cbuf + lr * 64 + chunk);
            }
        }
    } else {
        // ---- gemm2: M 16 mb x N 3 nb(256 of 768) x splitK4 (K=768 each) ----
        int g = bid - 150;
        int mb = g / 12;
        int cc = g % 12;
        int nb = cc >> 2, ks = cc & 3;
        const bf16* ga[4]; const bf16* gb[4];
#pragma unroll
        for (int c = 0; c < 4; c++) {
            int rt = c * 64 + wv * 8 + srow;
            ga[c] = H   + (size_t)(mb * 256 + rt) * HID + ks * 768 + lch;
            gb[c] = W2t + (size_t)(nb * 256 + rt) * HID + ks * 768 + lch;
        }
        gemm_loop_8w<12>(ga, gb, smem, acc);
        __syncthreads();
#pragma unroll
        for (int j = 0; j < 4; j++)
#pragma unroll
            for (int i = 0; i < 8; i++)
#pragma unroll
                for (int rr = 0; rr < 4; rr++) {
                    int lr = i * 16 + ((lane >> 4) << 2) + rr;
                    cbuf[lr * 64 + j * 16 + (lane & 15)] = (bf16)acc[i][j][rr];
                }
        bf16* gp = part + (size_t)ks * ROWS * DIM
                 + (size_t)(mb * 256 + wm * 128) * DIM + nb * 256 + wn * 64;
#pragma unroll
        for (int p = 0; p < 16; p++) {
            int lr = p * 8 + srow;
            int chunk = (lane & 7) * 8;
            *(bf16x8*)(gp + (size_t)lr * DIM + chunk) = *(const bf16x8*)(cbuf + lr * 64 + chunk);
        }
    }
}

// ---------------- combine: out = (1-mix)*(p0+p1+p2+p3+b2) + mix*apart ----------------
__global__ __launch_bounds__(256) void combine_kernel(const bf16* __restrict__ part,
                                                      const bf16* __restrict__ apart,
                                                      const float* __restrict__ b2,
                                                      const float* __restrict__ mix,
                                                      float* __restrict__ out) {
    int i = blockIdx.x * 256 + threadIdx.x;
    int base = i * 4;
    int row = base / DIM;
    int c = base - row * DIM;
    float mx = mix[row & (SEQ - 1)];
    bf16x4 p0 = *(const bf16x4*)(part + base);
    bf16x4 p1 = *(const bf16x4*)(part + (size_t)ROWS * DIM + base);
    bf16x4 p2 = *(const bf16x4*)(part + (size_t)2 * ROWS * DIM + base);
    bf16x4 p3 = *(const bf16x4*)(part + (size_t)3 * ROWS * DIM + base);
    bf16x4 a0 = *(const bf16x4*)(apart + base);
    float4 o;
    float* po = &o.x;
#pragma unroll
    for (int k = 0; k < 4; k++) {
        float main_v = (float)p0[k] + (float)p1[k] + (float)p2[k] + (float)p3[k] + b2[c + k];
        po[k] = (1.0f - mx) * main_v + mx * (float)a0[k];
    }
    *(float4*)(out + base) = o;
}

// ---------------- launch ----------------
extern "C" void kernel_launch(void* const* d_in, const int* in_sizes, int n_in,
                              void* d_out, int out_size, void* d_ws, size_t ws_size,
                              hipStream_t stream) {
    const float* x    = (const float*)d_in[0];
    const int* levels = (const int*)d_in[1];
    const float* gamma= (const float*)d_in[2];
    const float* beta = (const float*)d_in[3];
    const float* W1   = (const float*)d_in[4];
    const float* b1   = (const float*)d_in[5];
    const float* W2   = (const float*)d_in[6];
    const float* b2   = (const float*)d_in[7];
    const float* A1   = (const float*)d_in[8];
    const float* a1b  = (const float*)d_in[9];
    const float* A2   = (const float*)d_in[10];
    const float* a2b  = (const float*)d_in[11];
    const float* lmw  = (const float*)d_in[12];
    float* out = (float*)d_out;

    char* p = (char*)d_ws;
    auto alloc = [&](size_t bytes) {
        char* r = p;
        p += (bytes + 255) & ~(size_t)255;
        return r;
    };
    bf16* Xn   = (bf16*)alloc((size_t)ROWS * DIM * 2);
    bf16* W1t  = (bf16*)alloc((size_t)HID * DIM * 2);
    bf16* W2t  = (bf16*)alloc((size_t)DIM * HID * 2);
    bf16* A1t  = (bf16*)alloc((size_t)NLEV * HID2 * DIM * 2);
    bf16* A2t  = (bf16*)alloc((size_t)NLEV * DIM * HID2 * 2);
    bf16* H    = (bf16*)alloc((size_t)ROWS * HID * 2);
    bf16* HL   = (bf16*)alloc((size_t)MAXPAD2 * HID2 * 2);
    bf16* part = (bf16*)alloc((size_t)4 * ROWS * DIM * 2);
    bf16* apart= (bf16*)alloc((size_t)ROWS * DIM * 2);
    float* mix = (float*)alloc(SEQ * 4);
    int* row_index = (int*)alloc(MAXPAD2 * 4);
    int* tile_meta = (int*)alloc(32 * 4);
    float* zbuf    = (float*)alloc(4096);   // 4 KB zero page

    // prep: routing(1) + LN4(1024) + W1t(576) + A1t(2592) + W2t(576) + A2t(2592)
    prep_kernel<<<dim3(1 + 1024 + 576 + 2592 + 576 + 2592), dim3(256), 0, stream>>>(
        x, levels, gamma, beta, W1, A1, W2, A2, lmw,
        Xn, W1t, A1t, W2t, A2t, mix, row_index, tile_meta, zbuf);

    // mlp1: gemm1(192) + agemm1(150), 256^2 8-wave, 128 KB dynamic LDS
    mlp1_kernel<<<dim3(342), dim3(512), 131072, stream>>>(
        Xn, W1t, b1, H, A1t, a1b, row_index, tile_meta, (const bf16*)zbuf, HL);

    // mlp2: agemm2(150, KT=24) + gemm2 splitK4(192, KT=12)
    mlp2_kernel<<<dim3(342), dim3(512), 131072, stream>>>(
        H, W2t, part, HL, A2t, a2b, row_index, tile_meta, apart);

    combine_kernel<<<dim3(ROWS * DIM / 1024), dim3(256), 0, stream>>>(
        part, apart, b2, mix, out);
}

// Round 5
// 298.231 us; speedup vs baseline: 1.0461x; 1.0461x over previous
//
#include <hip/hip_runtime.h>
#include <hip/hip_bf16.h>
#include <math.h>

typedef __bf16 bf16;
typedef __bf16 bf16x4 __attribute__((ext_vector_type(4)));
typedef __bf16 bf16x8 __attribute__((ext_vector_type(8)));
typedef float f32x4 __attribute__((ext_vector_type(4)));

#define DIM 768
#define HID 3072
#define HID2 1536
#define NLEV 9
#define SEQ 2048
#define ROWS 4096            // BATCH*SEQ
#define MAXPAD 5248          // ROWS + NLEV*128 (rounded)
#define MAXTILES 41          // MAXPAD/128

// ---------------- async global->LDS 16B ----------------
__device__ __forceinline__ void gld16(const void* g, void* l) {
    __builtin_amdgcn_global_load_lds(
        (const __attribute__((address_space(1))) void*)g,
        (__attribute__((address_space(3))) void*)l, 16, 0, 0);
}

// fast tanh-GELU: max |err| vs exact-erf gelu ~5e-4
__device__ __forceinline__ float fast_gelu(float v) {
    float v2 = v * v;
    float twou = v * (1.59576912f + 0.071354816f * v2);
    float t = __expf(twou);
    return v * t / (t + 1.0f);
}

// T1: XCD-bijective swizzle (m204)
__device__ __forceinline__ int xcd_swizzle(int s, int nwg) {
    int q = nwg >> 3, r = nwg & 7;
    int x = s & 7, i = s >> 3;
    return (x < r ? x * (q + 1) : r * (q + 1) + (x - r) * q) + i;
}

// ================= PREP bodies =================

// LayerNorm, one WAVE per row (no barriers, no LDS).
__device__ __forceinline__ void ln_row(int row,
                                       const float* __restrict__ x,
                                       const float* __restrict__ gamma,
                                       const float* __restrict__ beta,
                                       bf16* __restrict__ xn) {
    int ln = threadIdx.x & 63;
    const float* xr = x + (size_t)row * DIM;
    int c = ln * 4;
    float4 v0 = *(const float4*)(xr + c);
    float4 v1 = *(const float4*)(xr + c + 256);
    float4 v2 = *(const float4*)(xr + c + 512);
    float s = v0.x + v0.y + v0.z + v0.w
            + v1.x + v1.y + v1.z + v1.w
            + v2.x + v2.y + v2.z + v2.w;
    float q = v0.x * v0.x + v0.y * v0.y + v0.z * v0.z + v0.w * v0.w
            + v1.x * v1.x + v1.y * v1.y + v1.z * v1.z + v1.w * v1.w
            + v2.x * v2.x + v2.y * v2.y + v2.z * v2.z + v2.w * v2.w;
#pragma unroll
    for (int off = 32; off; off >>= 1) {
        s += __shfl_xor(s, off, 64);
        q += __shfl_xor(q, off, 64);
    }
    float m = s * (1.0f / DIM);
    float r = rsqrtf(q * (1.0f / DIM) - m * m + 1e-5f);
    bf16* xo = xn + (size_t)row * DIM;
#pragma unroll
    for (int p = 0; p < 3; p++) {
        int cc = c + p * 256;
        float4 v = (p == 0) ? v0 : (p == 1) ? v1 : v2;
        float4 g = *(const float4*)(gamma + cc);
        float4 b = *(const float4*)(beta + cc);
        bf16x4 o;
        o[0] = (bf16)((v.x - m) * r * g.x + b.x);
        o[1] = (bf16)((v.y - m) * r * g.y + b.y);
        o[2] = (bf16)((v.z - m) * r * g.z + b.z);
        o[3] = (bf16)((v.w - m) * r * g.w + b.w);
        *(bf16x4*)(xo + cc) = o;
    }
}

// 64x256 strip transpose: 4 consecutive 64x64 tiles (same by), double-buffered
// LDS [2][64*68] -> 1 barrier per tile. fp32 [R][C] -> bf16 [C][R].
__device__ __forceinline__ void transpose_strip4(bf16* sm,
                                                 const float* __restrict__ inb,
                                                 bf16* __restrict__ outb,
                                                 int R, int C, int bx0, int by) {
    int tid = threadIdx.x;
    int ty = tid >> 4;
    int tx4 = (tid & 15) * 4;
    int ch = tid & 7;
    int ocb = tid >> 3;
#pragma unroll
    for (int s = 0; s < 4; s++) {
        int bx = bx0 + s;
        bf16* buf = sm + (s & 1) * (64 * 68);
#pragma unroll
        for (int p = 0; p < 4; p++) {
            int rloc = p * 16 + ty;
            float4 v = *(const float4*)(inb + (size_t)(by * 64 + rloc) * C + bx * 64 + tx4);
            bf16x4 o;
            o[0] = (bf16)v.x; o[1] = (bf16)v.y; o[2] = (bf16)v.z; o[3] = (bf16)v.w;
            *(bf16x4*)(buf + rloc * 68 + tx4) = o;
        }
        __syncthreads();
#pragma unroll
        for (int p = 0; p < 2; p++) {
            int oc = p * 32 + ocb;
            bf16x8 tmp;
#pragma unroll
            for (int k = 0; k < 8; k++) tmp[k] = buf[(ch * 8 + k) * 68 + oc];
            *(bf16x8*)(outb + (size_t)(bx * 64 + oc) * R + by * 64 + ch * 8) = tmp;
        }
        // per-thread program order (read s -> barrier(s+1) -> write s+2) makes
        // single-barrier-per-tile safe with the 2-buffer rotation
    }
}

__device__ __forceinline__ void routing_body(float* sm,
                                             const int* __restrict__ levels_info,
                                             const float* __restrict__ lmw,
                                             float* __restrict__ mix,
                                             int* __restrict__ row_index,
                                             int* __restrict__ tile_meta,
                                             float* __restrict__ zbuf) {
    int* cnt = (int*)sm;
    int* cur = cnt + NLEV;
    int* off = cur + NLEV;
    float* mixv = (float*)(off + NLEV);
    int tid = threadIdx.x;
    if (tid < NLEV) { cnt[tid] = 0; cur[tid] = 0; }
    __syncthreads();
    for (int s = tid; s < SEQ; s += 256) {
        int d = levels_info[s * 4];
        d = d < 0 ? 0 : (d > 8 ? 8 : d);
        atomicAdd(&cnt[d], 1);
    }
    for (int i = tid; i < MAXPAD; i += 256) row_index[i] = -1;
    for (int i = tid; i < 1024; i += 256) zbuf[i] = 0.0f;   // 4 KB zero page
    __syncthreads();
    if (tid == 0) {
        float mx = lmw[0];
        for (int l = 1; l < NLEV; l++) mx = fmaxf(mx, lmw[l]);
        float denom = 0.f;
        for (int l = 0; l < NLEV; l++) denom += (float)cnt[l] * expf(lmw[l] - mx);
        float inv = 1.0f / denom;
        int running = 0, t = 0;
        for (int l = 0; l < NLEV; l++) {
            mixv[l] = expf(lmw[l] - mx) * inv;
            off[l] = running;
            int seg = (2 * cnt[l] + 127) & ~127;
            for (int k = 0; k < seg / 128; k++) tile_meta[t++] = l;
            running += seg;
        }
        for (; t < MAXTILES; t++) tile_meta[t] = -1;
    }
    __syncthreads();
    for (int s = tid; s < SEQ; s += 256) {
        int d = levels_info[s * 4];
        d = d < 0 ? 0 : (d > 8 ? 8 : d);
        int p = atomicAdd(&cur[d], 2);
        row_index[off[d] + p]     = s;
        row_index[off[d] + p + 1] = s + SEQ;
        mix[s] = mixv[d];
    }
}

// ---------------- prep: routing(1) + LN16(256) + strip transposes(1584) ----------------
// grid = 1 + 256 + 144 (W1) + 648 (A1) + 144 (W2) + 648 (A2) = 1841
__global__ __launch_bounds__(256) void prep_kernel(const float* __restrict__ x,
                                                   const int* __restrict__ levels_info,
                                                   const float* __restrict__ gamma,
                                                   const float* __restrict__ beta,
                                                   const float* __restrict__ W1,
                                                   const float* __restrict__ A1,
                                                   const float* __restrict__ W2,
                                                   const float* __restrict__ A2,
                                                   const float* __restrict__ lmw,
                                                   bf16* __restrict__ Xn,
                                                   bf16* __restrict__ W1t,
                                                   bf16* __restrict__ A1t,
                                                   bf16* __restrict__ W2t,
                                                   bf16* __restrict__ A2t,
                                                   float* __restrict__ mix,
                                                   int* __restrict__ row_index,
                                                   int* __restrict__ tile_meta,
                                                   float* __restrict__ zbuf) {
    __shared__ __align__(16) bf16 tsm[2 * 64 * 68];   // 17.4 KB
    int b = blockIdx.x;
    if (b == 0) { routing_body((float*)tsm, levels_info, lmw, mix, row_index, tile_meta, zbuf); return; }
    b -= 1;
    if (b < 256) {  // 16 rows per block, 4 per wave
        int wv = threadIdx.x >> 6;
#pragma unroll
        for (int it = 0; it < 4; it++)
            ln_row(b * 16 + wv * 4 + it, x, gamma, beta, Xn);
        return;
    }
    b -= 256;
    if (b < 144) {  // W1 [768,3072] -> [3072,768]: bx<48, by<12
        transpose_strip4(tsm, W1, W1t, DIM, HID, (b % 12) * 4, b / 12);
        return;
    }
    b -= 144;
    if (b < 648) {  // A1[lvl] [768,1536] -> [1536,768]: bx<24, by<12 -> 72 strips/level
        int bz = b / 72, r = b % 72;
        transpose_strip4(tsm, A1 + (size_t)bz * DIM * HID2, A1t + (size_t)bz * DIM * HID2,
                         DIM, HID2, (r % 6) * 4, r / 6);
        return;
    }
    b -= 648;
    if (b < 144) {  // W2 [3072,768] -> [768,3072]: bx<12, by<48
        transpose_strip4(tsm, W2, W2t, HID, DIM, (b % 3) * 4, b / 3);
        return;
    }
    b -= 144;
    {   // A2[lvl] [1536,768] -> [768,1536]: bx<12, by<24 -> 72 strips/level
        int bz = b / 72, r = b % 72;
        transpose_strip4(tsm, A2 + (size_t)bz * HID2 * DIM, A2t + (size_t)bz * HID2 * DIM,
                         HID2, DIM, (r % 3) * 4, r / 3);
    }
}

// ---------------- BK=64 double-buffered GEMM K-loop (round-3 verified) ----------------
template<int KT>   // KT = K/64
__device__ __forceinline__ void gemm_loop_db64(const bf16* (&ga)[4], const bf16* (&gb)[4],
                                               bf16* As, bf16* Bs,
                                               f32x4 (&acc)[4][4]) {
    int tid = threadIdx.x;
    int wv = tid >> 6;
    int lane = tid & 63;
    int wm = wv >> 1, wn = wv & 1;
    int r = lane & 15;
    int ch0 = ((lane >> 4) ^ (lane & 7)) * 8;          // swizzled k-chunk, k32=0
    int aoff = (wm * 64 + r) * 64 + ch0;
    int boff = (wn * 64 + r) * 64 + ch0;
#pragma unroll
    for (int c = 0; c < 4; c++) {
        gld16(ga[c], As + (c * 32 + wv * 8) * 64);
        gld16(gb[c], Bs + (c * 32 + wv * 8) * 64);
        ga[c] += 64; gb[c] += 64;
    }
#pragma unroll
    for (int kt = 0; kt < KT; ++kt) {
        __syncthreads();
        const int cur = (kt & 1) << 13;
        const int nxt = cur ^ 8192;
        if (kt + 1 < KT) {
#pragma unroll
            for (int c = 0; c < 4; c++) {
                gld16(ga[c], As + nxt + (c * 32 + wv * 8) * 64);
                gld16(gb[c], Bs + nxt + (c * 32 + wv * 8) * 64);
                ga[c] += 64; gb[c] += 64;
            }
        }
#pragma unroll
        for (int k32 = 0; k32 < 2; k32++) {
            const int kx = k32 << 5;
            bf16x8 af[4], bfr[4];
#pragma unroll
            for (int i = 0; i < 4; i++) af[i] = *(const bf16x8*)(As + cur + ((aoff + i * 1024) ^ kx));
#pragma unroll
            for (int j = 0; j < 4; j++) bfr[j] = *(const bf16x8*)(Bs + cur + ((boff + j * 1024) ^ kx));
#pragma unroll
            for (int i = 0; i < 4; i++)
#pragma unroll
                for (int j = 0; j < 4; j++)
                    acc[i][j] = __builtin_amdgcn_mfma_f32_16x16x32_bf16(af[i], bfr[j], acc[i][j], 0, 0, 0);
        }
    }
}

#define ACC_INIT(acc) \
    _Pragma("unroll") for (int i = 0; i < 4; i++) \
    _Pragma("unroll") for (int j = 0; j < 4; j++) acc[i][j] = (f32x4){0.f, 0.f, 0.f, 0.f};

// contiguous 128B-row store of a wave's 64x64 bf16 tile staged in cbuf
__device__ __forceinline__ void store_tile(const bf16* cbuf, int lane,
                                           bf16* gptr, int ldg) {
#pragma unroll
    for (int p = 0; p < 8; p++) {
        int lrow = p * 8 + (lane >> 3);
        int chunk = (lane & 7) * 8;
        bf16x8 v = *(const bf16x8*)(cbuf + lrow * 64 + chunk);
        *(bf16x8*)(gptr + (size_t)lrow * ldg + chunk) = v;
    }
}

// ---------------- mlp1: PURE GEMM — gemm1(768, clustered) + agemm1(492) ----------------
__global__ __launch_bounds__(256) void mlp1_kernel(const bf16* __restrict__ Xn,
                                                   const bf16* __restrict__ W1t,
                                                   const float* __restrict__ b1,
                                                   bf16* __restrict__ H,
                                                   const bf16* __restrict__ A1t,
                                                   const float* __restrict__ a1b,
                                                   const int* __restrict__ row_index,
                                                   const int* __restrict__ tile_meta,
                                                   const bf16* __restrict__ zbuf,
                                                   bf16* __restrict__ HL) {
    __shared__ __align__(16) bf16 smem[32768];   // 64 KB
    bf16* As = smem;
    bf16* Bs = smem + 16384;
    int bid = xcd_swizzle(blockIdx.x, 1260);
    int tid = threadIdx.x;
    int lane = tid & 63, wv = tid >> 6, wm = wv >> 1, wn = wv & 1;
    int lrow = lane >> 3;                       // 0..7 row within 8-row group
    int lch = ((lane & 7) ^ lrow) * 8;          // pre-swizzled global chunk
    bf16* cbuf = smem + wv * 4096;

    if (bid < 768) {
        // ---- gemm1: 24 clusters of 4nb x 8mb (2.4 MB working set, XCD-L2-fit) ----
        int s = bid >> 5, u = bid & 31;
        int nb = (s % 6) * 4 + (u & 3);
        int mb = (s / 6) * 8 + (u >> 2);
        f32x4 acc[4][4];
        ACC_INIT(acc);
        const bf16* ga[4]; const bf16* gb[4];
#pragma unroll
        for (int c = 0; c < 4; c++) {
            int rt = c * 32 + wv * 8 + lrow;
            ga[c] = Xn  + (size_t)(mb * 128 + rt) * DIM + lch;
            gb[c] = W1t + (size_t)(nb * 128 + rt) * DIM + lch;
        }
        gemm_loop_db64<12>(ga, gb, As, Bs, acc);
        int cbase = nb * 128 + wn * 64 + (lane & 15);
        __syncthreads();
#pragma unroll
        for (int j = 0; j < 4; j++) {
            float bias = b1[cbase + j * 16];
#pragma unroll
            for (int i = 0; i < 4; i++)
#pragma unroll
                for (int r = 0; r < 4; r++) {
                    int lr = i * 16 + ((lane >> 4) << 2) + r;
                    int lc = j * 16 + (lane & 15);
                    cbuf[lr * 64 + lc] = (bf16)fast_gelu(acc[i][j][r] + bias);
                }
        }
        __syncthreads();
        store_tile(cbuf, lane, H + (size_t)(mb * 128 + wm * 64) * HID + nb * 128 + wn * 64, HID);
    } else {
        // ---- agemm1: 41 tiles x 12 N ----
        int t2 = bid - 768;
        int nb = t2 % 12, t = t2 / 12;
        int lvl = tile_meta[t];
        if (lvl < 0) return;
        f32x4 acc[4][4];
        ACC_INIT(acc);
        const bf16* ga[4]; const bf16* gb[4];
        const bf16* Bl = A1t + (size_t)lvl * HID2 * DIM;
#pragma unroll
        for (int c = 0; c < 4; c++) {
            int rt = c * 32 + wv * 8 + lrow;
            int rg = row_index[t * 128 + rt];
            ga[c] = (rg >= 0) ? (Xn + (size_t)rg * DIM + lch) : (zbuf + lch);
            gb[c] = Bl + (size_t)(nb * 128 + rt) * DIM + lch;
        }
        gemm_loop_db64<12>(ga, gb, As, Bs, acc);
        int cbase = nb * 128 + wn * 64 + (lane & 15);
        __syncthreads();
#pragma unroll
        for (int j = 0; j < 4; j++) {
            float bias = a1b[lvl * HID2 + cbase + j * 16];
#pragma unroll
            for (int i = 0; i < 4; i++)
#pragma unroll
                for (int r = 0; r < 4; r++) {
                    int lr = i * 16 + ((lane >> 4) << 2) + r;
                    int lc = j * 16 + (lane & 15);
                    cbuf[lr * 64 + lc] = (bf16)fmaxf(acc[i][j][r] + bias, 0.0f);
                }
        }
        __syncthreads();
        store_tile(cbuf, lane, HL + (size_t)(t * 128 + wm * 64) * HID2 + nb * 128 + wn * 64, HID2);
    }
}

// ---------------- mlp2: gemm2 splitK2 (KT=24) + agemm2 (KT=24) ----------------
__global__ __launch_bounds__(256) void mlp2_kernel(const bf16* __restrict__ H,
                                                   const bf16* __restrict__ W2t,
                                                   bf16* __restrict__ part,   // [2][ROWS*DIM]
                                                   const bf16* __restrict__ HL,
                                                   const bf16* __restrict__ A2t,
                                                   const float* __restrict__ a2b,
                                                   const int* __restrict__ row_index,
                                                   const int* __restrict__ tile_meta,
                                                   bf16* __restrict__ apart) { // [ROWS*DIM]
    __shared__ __align__(16) bf16 smem[32768];   // 64 KB
    bf16* As = smem;
    bf16* Bs = smem + 16384;
    int bid = xcd_swizzle(blockIdx.x, 384 + MAXTILES * 6);
    int tid = threadIdx.x;
    int lane = tid & 63, wv = tid >> 6, wm = wv >> 1, wn = wv & 1;
    int lrow = lane >> 3;
    int lch = ((lane & 7) ^ lrow) * 8;
    bf16* cbuf = smem + wv * 4096;
    f32x4 acc[4][4];
    ACC_INIT(acc);

    if (bid < 384) {
        // ---- gemm2: mb = bid/12 (12 consecutive blocks share the H chunk) ----
        int cc = bid % 12;
        int nb = cc >> 1, ks = cc & 1;
        int mb = bid / 12;
        const bf16* ga[4]; const bf16* gb[4];
#pragma unroll
        for (int c = 0; c < 4; c++) {
            int rt = c * 32 + wv * 8 + lrow;
            ga[c] = H   + (size_t)(mb * 128 + rt) * HID + ks * 1536 + lch;
            gb[c] = W2t + (size_t)(nb * 128 + rt) * HID + ks * 1536 + lch;
        }
        gemm_loop_db64<24>(ga, gb, As, Bs, acc);
        __syncthreads();
#pragma unroll
        for (int j = 0; j < 4; j++)
#pragma unroll
            for (int i = 0; i < 4; i++)
#pragma unroll
                for (int r = 0; r < 4; r++) {
                    int lr = i * 16 + ((lane >> 4) << 2) + r;
                    int lc = j * 16 + (lane & 15);
                    cbuf[lr * 64 + lc] = (bf16)acc[i][j][r];
                }
        __syncthreads();
        bf16* pk = part + (size_t)ks * ROWS * DIM;
        store_tile(cbuf, lane, pk + (size_t)(mb * 128 + wm * 64) * DIM + nb * 128 + wn * 64, DIM);
    } else {
        // ---- agemm2: 41 tiles x 6 N, full K=1536 ----
        int t2 = bid - 384;
        int nb = t2 % 6, t = t2 / 6;
        int lvl = tile_meta[t];
        if (lvl < 0) return;
        const bf16* ga[4]; const bf16* gb[4];
        const bf16* Bl = A2t + (size_t)lvl * DIM * HID2;
#pragma unroll
        for (int c = 0; c < 4; c++) {
            int rt = c * 32 + wv * 8 + lrow;
            ga[c] = HL + (size_t)(t * 128 + rt) * HID2 + lch;
            gb[c] = Bl + (size_t)(nb * 128 + rt) * HID2 + lch;
        }
        gemm_loop_db64<24>(ga, gb, As, Bs, acc);
        int cbase = nb * 128 + wn * 64 + (lane & 15);
        __syncthreads();
#pragma unroll
        for (int j = 0; j < 4; j++) {
            float bias = a2b[lvl * DIM + cbase + j * 16];
#pragma unroll
            for (int i = 0; i < 4; i++)
#pragma unroll
                for (int r = 0; r < 4; r++) {
                    int lr = i * 16 + ((lane >> 4) << 2) + r;
                    int lc = j * 16 + (lane & 15);
                    cbuf[lr * 64 + lc] = (bf16)(acc[i][j][r] + bias);
                }
        }
        __syncthreads();
        // gathered row store, still 128B-contiguous per row
        int colg = nb * 128 + wn * 64;
#pragma unroll
        for (int p = 0; p < 8; p++) {
            int lr = p * 8 + (lane >> 3);
            int chunk = (lane & 7) * 8;
            int rg = row_index[t * 128 + wm * 64 + lr];
            if (rg >= 0) {
                bf16x8 v = *(const bf16x8*)(cbuf + lr * 64 + chunk);
                *(bf16x8*)(apart + (size_t)rg * DIM + colg + chunk) = v;
            }
        }
    }
}

// ---------------- combine: out = (1-mix)*(p0+p1+b2) + mix*apart, 8 elems/thread ----------------
__global__ __launch_bounds__(256) void combine_kernel(const bf16* __restrict__ part,
                                                      const bf16* __restrict__ apart,
                                                      const float* __restrict__ b2,
                                                      const float* __restrict__ mix,
                                                      float* __restrict__ out) {
    int i = blockIdx.x * 256 + threadIdx.x;
    int base = i * 8;
    int row = base / DIM;
    int c = base - row * DIM;
    float mx = mix[row & (SEQ - 1)];
    bf16x8 p0 = *(const bf16x8*)(part + base);
    bf16x8 p1 = *(const bf16x8*)(part + (size_t)ROWS * DIM + base);
    bf16x8 a0 = *(const bf16x8*)(apart + base);
    float4 o0, o1;
    float* po0 = &o0.x;
    float* po1 = &o1.x;
#pragma unroll
    for (int k = 0; k < 4; k++) {
        float main_v = (float)p0[k] + (float)p1[k] + b2[c + k];
        po0[k] = (1.0f - mx) * main_v + mx * (float)a0[k];
    }
#pragma unroll
    for (int k = 0; k < 4; k++) {
        float main_v = (float)p0[4 + k] + (float)p1[4 + k] + b2[c + 4 + k];
        po1[k] = (1.0f - mx) * main_v + mx * (float)a0[4 + k];
    }
    *(float4*)(out + base) = o0;
    *(float4*)(out + base + 4) = o1;
}

// ---------------- launch ----------------
extern "C" void kernel_launch(void* const* d_in, const int* in_sizes, int n_in,
                              void* d_out, int out_size, void* d_ws, size_t ws_size,
                              hipStream_t stream) {
    const float* x    = (const float*)d_in[0];
    const int* levels = (const int*)d_in[1];
    const float* gamma= (const float*)d_in[2];
    const float* beta = (const float*)d_in[3];
    const float* W1   = (const float*)d_in[4];
    const float* b1   = (const float*)d_in[5];
    const float* W2   = (const float*)d_in[6];
    const float* b2   = (const float*)d_in[7];
    const float* A1   = (const float*)d_in[8];
    const float* a1b  = (const float*)d_in[9];
    const float* A2   = (const float*)d_in[10];
    const float* a2b  = (const float*)d_in[11];
    const float* lmw  = (const float*)d_in[12];
    float* out = (float*)d_out;

    char* p = (char*)d_ws;
    auto alloc = [&](size_t bytes) {
        char* r = p;
        p += (bytes + 255) & ~(size_t)255;
        return r;
    };
    bf16* Xn   = (bf16*)alloc((size_t)ROWS * DIM * 2);
    bf16* W1t  = (bf16*)alloc((size_t)HID * DIM * 2);
    bf16* W2t  = (bf16*)alloc((size_t)DIM * HID * 2);
    bf16* A1t  = (bf16*)alloc((size_t)NLEV * HID2 * DIM * 2);
    bf16* A2t  = (bf16*)alloc((size_t)NLEV * DIM * HID2 * 2);
    bf16* H    = (bf16*)alloc((size_t)ROWS * HID * 2);
    bf16* HL   = (bf16*)alloc((size_t)MAXPAD * HID2 * 2);
    bf16* part = (bf16*)alloc((size_t)2 * ROWS * DIM * 2);
    bf16* apart= (bf16*)alloc((size_t)ROWS * DIM * 2);
    float* mix = (float*)alloc(SEQ * 4);
    int* row_index = (int*)alloc(MAXPAD * 4);
    int* tile_meta = (int*)alloc(MAXTILES * 4);
    float* zbuf    = (float*)alloc(4096);   // 4 KB zero page

    // prep: routing(1) + LN16(256) + W1t(144) + A1t(648) + W2t(144) + A2t(648)
    prep_kernel<<<dim3(1 + 256 + 144 + 648 + 144 + 648), dim3(256), 0, stream>>>(
        x, levels, gamma, beta, W1, A1, W2, A2, lmw,
        Xn, W1t, A1t, W2t, A2t, mix, row_index, tile_meta, zbuf);

    // mlp1: pure GEMM — gemm1(768) + agemm1(492), BK=64, T1-swizzled
    mlp1_kernel<<<dim3(768 + 492), dim3(256), 0, stream>>>(
        Xn, W1t, b1, H, A1t, a1b, row_index, tile_meta, (const bf16*)zbuf, HL);

    // mlp2: gemm2 splitK2 (384, KT=24) + agemm2 (246, KT=24), BK=64, T1-swizzled
    mlp2_kernel<<<dim3(384 + MAXTILES * 6), dim3(256), 0, stream>>>(
        H, W2t, part, HL, A2t, a2b, row_index, tile_meta, apart);

    combine_kernel<<<dim3(ROWS * DIM / 2048), dim3(256), 0, stream>>>(
        part, apart, b2, mix, out);
}

// Round 6
// 263.122 us; speedup vs baseline: 1.1857x; 1.1334x over previous
//
#include <hip/hip_runtime.h>
#include <hip/hip_bf16.h>
#include <math.h>

typedef __bf16 bf16;
typedef __bf16 bf16x4 __attribute__((ext_vector_type(4)));
typedef __bf16 bf16x8 __attribute__((ext_vector_type(8)));
typedef float f32x4 __attribute__((ext_vector_type(4)));

#define DIM 768
#define HID 3072
#define HID2 1536
#define NLEV 9
#define SEQ 2048
#define ROWS 4096            // BATCH*SEQ
#define MAXPAD 5248          // ROWS + NLEV*128 (rounded)
#define MAXTILES 41          // MAXPAD/128

// ---------------- async global->LDS 16B ----------------
__device__ __forceinline__ void gld16(const void* g, void* l) {
    __builtin_amdgcn_global_load_lds(
        (const __attribute__((address_space(1))) void*)g,
        (__attribute__((address_space(3))) void*)l, 16, 0, 0);
}

// fast tanh-GELU: max |err| vs exact-erf gelu ~5e-4
__device__ __forceinline__ float fast_gelu(float v) {
    float v2 = v * v;
    float twou = v * (1.59576912f + 0.071354816f * v2);
    float t = __expf(twou);
    return v * t / (t + 1.0f);
}

// T1: XCD-bijective swizzle (m204). Dispatch slot s -> work id, so each XCD's
// slots (s%8 round-robin) receive a CONTIGUOUS work chunk (L2 locality).
__device__ __forceinline__ int xcd_swizzle(int s, int nwg) {
    int q = nwg >> 3, r = nwg & 7;
    int x = s & 7, i = s >> 3;
    return (x < r ? x * (q + 1) : r * (q + 1) + (x - r) * q) + i;
}

// ================= PREP bodies =================

// LayerNorm, one WAVE per row (no barriers, no LDS). Block = 4 waves = 4 rows.
__device__ __forceinline__ void ln4_body(int blk,
                                         const float* __restrict__ x,
                                         const float* __restrict__ gamma,
                                         const float* __restrict__ beta,
                                         bf16* __restrict__ xn) {
    int tid = threadIdx.x;
    int wv = tid >> 6, ln = tid & 63;
    int row = blk * 4 + wv;
    const float* xr = x + (size_t)row * DIM;
    int c = ln * 4;
    float4 v0 = *(const float4*)(xr + c);
    float4 v1 = *(const float4*)(xr + c + 256);
    float4 v2 = *(const float4*)(xr + c + 512);
    float s = v0.x + v0.y + v0.z + v0.w
            + v1.x + v1.y + v1.z + v1.w
            + v2.x + v2.y + v2.z + v2.w;
    float q = v0.x * v0.x + v0.y * v0.y + v0.z * v0.z + v0.w * v0.w
            + v1.x * v1.x + v1.y * v1.y + v1.z * v1.z + v1.w * v1.w
            + v2.x * v2.x + v2.y * v2.y + v2.z * v2.z + v2.w * v2.w;
#pragma unroll
    for (int off = 32; off; off >>= 1) {
        s += __shfl_xor(s, off, 64);
        q += __shfl_xor(q, off, 64);
    }
    float m = s * (1.0f / DIM);
    float r = rsqrtf(q * (1.0f / DIM) - m * m + 1e-5f);
    bf16* xo = xn + (size_t)row * DIM;
#pragma unroll
    for (int p = 0; p < 3; p++) {
        int cc = c + p * 256;
        float4 v = (p == 0) ? v0 : (p == 1) ? v1 : v2;
        float4 g = *(const float4*)(gamma + cc);
        float4 b = *(const float4*)(beta + cc);
        bf16x4 o;
        o[0] = (bf16)((v.x - m) * r * g.x + b.x);
        o[1] = (bf16)((v.y - m) * r * g.y + b.y);
        o[2] = (bf16)((v.z - m) * r * g.z + b.z);
        o[3] = (bf16)((v.w - m) * r * g.w + b.w);
        *(bf16x4*)(xo + cc) = o;
    }
}

// 64x64 tile transpose: fp32 [R][C] -> bf16 [C][R]. bf16 LDS [64][68] (8.4 KB).
__device__ __forceinline__ void transpose_body64(bf16* sm,
                                                 const float* __restrict__ inb,
                                                 bf16* __restrict__ outb,
                                                 int R, int C, int bx, int by) {
    int tid = threadIdx.x;
    int ty = tid >> 4;
    int tx4 = (tid & 15) * 4;
#pragma unroll
    for (int p = 0; p < 4; p++) {
        int rloc = p * 16 + ty;
        int row = by * 64 + rloc;
        float4 v = *(const float4*)(inb + (size_t)row * C + bx * 64 + tx4);
        bf16x4 o;
        o[0] = (bf16)v.x; o[1] = (bf16)v.y; o[2] = (bf16)v.z; o[3] = (bf16)v.w;
        *(bf16x4*)(sm + rloc * 68 + tx4) = o;
    }
    __syncthreads();
    int ch = tid & 7;
    int ocb = tid >> 3;
#pragma unroll
    for (int p = 0; p < 2; p++) {
        int oc = p * 32 + ocb;
        bf16x8 tmp;
#pragma unroll
        for (int k = 0; k < 8; k++) tmp[k] = sm[(ch * 8 + k) * 68 + oc];
        *(bf16x8*)(outb + (size_t)(bx * 64 + oc) * R + by * 64 + ch * 8) = tmp;
    }
}

__device__ __forceinline__ void routing_body(float* sm,
                                             const int* __restrict__ levels_info,
                                             const float* __restrict__ lmw,
                                             float* __restrict__ mix,
                                             int* __restrict__ row_index,
                                             int* __restrict__ tile_meta,
                                             float* __restrict__ zbuf) {
    int* cnt = (int*)sm;
    int* cur = cnt + NLEV;
    int* off = cur + NLEV;
    float* mixv = (float*)(off + NLEV);
    int tid = threadIdx.x;
    if (tid < NLEV) { cnt[tid] = 0; cur[tid] = 0; }
    __syncthreads();
    for (int s = tid; s < SEQ; s += 256) {
        int d = levels_info[s * 4];
        d = d < 0 ? 0 : (d > 8 ? 8 : d);
        atomicAdd(&cnt[d], 1);
    }
    for (int i = tid; i < MAXPAD; i += 256) row_index[i] = -1;
    for (int i = tid; i < 1024; i += 256) zbuf[i] = 0.0f;   // 4 KB zero page
    __syncthreads();
    if (tid == 0) {
        float mx = lmw[0];
        for (int l = 1; l < NLEV; l++) mx = fmaxf(mx, lmw[l]);
        float denom = 0.f;
        for (int l = 0; l < NLEV; l++) denom += (float)cnt[l] * expf(lmw[l] - mx);
        float inv = 1.0f / denom;
        int running = 0, t = 0;
        for (int l = 0; l < NLEV; l++) {
            mixv[l] = expf(lmw[l] - mx) * inv;
            off[l] = running;
            int seg = (2 * cnt[l] + 127) & ~127;
            for (int k = 0; k < seg / 128; k++) tile_meta[t++] = l;
            running += seg;
        }
        for (; t < MAXTILES; t++) tile_meta[t] = -1;
    }
    __syncthreads();
    for (int s = tid; s < SEQ; s += 256) {
        int d = levels_info[s * 4];
        d = d < 0 ? 0 : (d > 8 ? 8 : d);
        int p = atomicAdd(&cur[d], 2);
        row_index[off[d] + p]     = s;
        row_index[off[d] + p + 1] = s + SEQ;
        mix[s] = mixv[d];
    }
}

// ---------------- prep: routing + LN + ALL weight transposes ----------------
__global__ __launch_bounds__(256) void prep_kernel(const float* __restrict__ x,
                                                   const int* __restrict__ levels_info,
                                                   const float* __restrict__ gamma,
                                                   const float* __restrict__ beta,
                                                   const float* __restrict__ W1,
                                                   const float* __restrict__ A1,
                                                   const float* __restrict__ W2,
                                                   const float* __restrict__ A2,
                                                   const float* __restrict__ lmw,
                                                   bf16* __restrict__ Xn,
                                                   bf16* __restrict__ W1t,
                                                   bf16* __restrict__ A1t,
                                                   bf16* __restrict__ W2t,
                                                   bf16* __restrict__ A2t,
                                                   float* __restrict__ mix,
                                                   int* __restrict__ row_index,
                                                   int* __restrict__ tile_meta,
                                                   float* __restrict__ zbuf) {
    __shared__ __align__(16) bf16 tsm[64 * 68];
    int b = blockIdx.x;
    if (b == 0) { routing_body((float*)tsm, levels_info, lmw, mix, row_index, tile_meta, zbuf); return; }
    b -= 1;
    if (b < 1024) { ln4_body(b, x, gamma, beta, Xn); return; }
    b -= 1024;
    if (b < 576) {
        transpose_body64(tsm, W1, W1t, DIM, HID, b % 48, b / 48);
        return;
    }
    b -= 576;
    if (b < 2592) {
        int bz = b / 288, r = b % 288;
        transpose_body64(tsm, A1 + (size_t)bz * DIM * HID2, A1t + (size_t)bz * DIM * HID2,
                         DIM, HID2, r % 24, r / 24);
        return;
    }
    b -= 2592;
    if (b < 576) {
        transpose_body64(tsm, W2, W2t, HID, DIM, b % 12, b / 12);
        return;
    }
    b -= 576;
    {
        int bz = b / 288, r = b % 288;
        transpose_body64(tsm, A2 + (size_t)bz * HID2 * DIM, A2t + (size_t)bz * HID2 * DIM,
                         HID2, DIM, r % 12, r / 12);
    }
}

// ---------------- BK=64 double-buffered GEMM K-loop ----------------
// LDS: As = 2 x 8192 elems (16 KB each), Bs same -> 64 KB total.
// Producer: gld16 writes LINEAR LDS (wave-uniform base + lane*16B), 8 rows x
// 128B per call; the XOR swizzle (chunk ^= row&7) is applied on the per-lane
// GLOBAL source address (m173 pattern). Each 8-lane group covers one aligned
// 128B row window -> full-width HBM requests.
// Consumer: ds_read_b128 at chunk' = ((k32<<2)|kc) ^ (lane&7) -> <=2-way bank
// conflicts (free). Half the barriers/vmcnt-drains of the BK=32 loop.
template<int KT>   // KT = K/64
__device__ __forceinline__ void gemm_loop_db64(const bf16* (&ga)[4], const bf16* (&gb)[4],
                                               bf16* As, bf16* Bs,
                                               f32x4 (&acc)[4][4]) {
    int tid = threadIdx.x;
    int wv = tid >> 6;
    int lane = tid & 63;
    int wm = wv >> 1, wn = wv & 1;
    int r = lane & 15;
    int ch0 = ((lane >> 4) ^ (lane & 7)) * 8;          // swizzled k-chunk, k32=0
    int aoff = (wm * 64 + r) * 64 + ch0;
    int boff = (wn * 64 + r) * 64 + ch0;
#pragma unroll
    for (int c = 0; c < 4; c++) {
        gld16(ga[c], As + (c * 32 + wv * 8) * 64);
        gld16(gb[c], Bs + (c * 32 + wv * 8) * 64);
        ga[c] += 64; gb[c] += 64;
    }
#pragma unroll
    for (int kt = 0; kt < KT; ++kt) {
        __syncthreads();
        const int cur = (kt & 1) << 13;
        const int nxt = cur ^ 8192;
        if (kt + 1 < KT) {
#pragma unroll
            for (int c = 0; c < 4; c++) {
                gld16(ga[c], As + nxt + (c * 32 + wv * 8) * 64);
                gld16(gb[c], Bs + nxt + (c * 32 + wv * 8) * 64);
                ga[c] += 64; gb[c] += 64;
            }
        }
#pragma unroll
        for (int k32 = 0; k32 < 2; k32++) {
            const int kx = k32 << 5;                   // XOR 32 elems = k-chunk bit2
            bf16x8 af[4], bfr[4];
#pragma unroll
            for (int i = 0; i < 4; i++) af[i] = *(const bf16x8*)(As + cur + ((aoff + i * 1024) ^ kx));
#pragma unroll
            for (int j = 0; j < 4; j++) bfr[j] = *(const bf16x8*)(Bs + cur + ((boff + j * 1024) ^ kx));
#pragma unroll
            for (int i = 0; i < 4; i++)
#pragma unroll
                for (int j = 0; j < 4; j++)
                    acc[i][j] = __builtin_amdgcn_mfma_f32_16x16x32_bf16(af[i], bfr[j], acc[i][j], 0, 0, 0);
        }
    }
}

#define ACC_INIT(acc) \
    _Pragma("unroll") for (int i = 0; i < 4; i++) \
    _Pragma("unroll") for (int j = 0; j < 4; j++) acc[i][j] = (f32x4){0.f, 0.f, 0.f, 0.f};

// contiguous 128B-row store of a wave's 64x64 bf16 tile staged in cbuf
__device__ __forceinline__ void store_tile(const bf16* cbuf, int lane,
                                           bf16* gptr, int ldg) {
#pragma unroll
    for (int p = 0; p < 8; p++) {
        int lrow = p * 8 + (lane >> 3);
        int chunk = (lane & 7) * 8;
        bf16x8 v = *(const bf16x8*)(cbuf + lrow * 64 + chunk);
        *(bf16x8*)(gptr + (size_t)lrow * ldg + chunk) = v;
    }
}

// ---------------- mlp1: PURE GEMM — gemm1(768, clustered) + agemm1(492) ----------------
__global__ __launch_bounds__(256) void mlp1_kernel(const bf16* __restrict__ Xn,
                                                   const bf16* __restrict__ W1t,
                                                   const float* __restrict__ b1,
                                                   bf16* __restrict__ H,
                                                   const bf16* __restrict__ A1t,
                                                   const float* __restrict__ a1b,
                                                   const int* __restrict__ row_index,
                                                   const int* __restrict__ tile_meta,
                                                   const bf16* __restrict__ zbuf,
                                                   bf16* __restrict__ HL) {
    __shared__ __align__(16) bf16 smem[32768];   // 64 KB
    bf16* As = smem;
    bf16* Bs = smem + 16384;
    int bid = xcd_swizzle(blockIdx.x, 1260);
    int tid = threadIdx.x;
    int lane = tid & 63, wv = tid >> 6, wm = wv >> 1, wn = wv & 1;
    int lrow = lane >> 3;                       // 0..7 row within 8-row group
    int lch = ((lane & 7) ^ lrow) * 8;          // pre-swizzled global chunk
    bf16* cbuf = smem + wv * 4096;

    if (bid < 768) {
        // ---- gemm1: 24 clusters of 4nb x 8mb (2.4 MB working set, XCD-L2-fit) ----
        int s = bid >> 5, u = bid & 31;
        int nb = (s % 6) * 4 + (u & 3);
        int mb = (s / 6) * 8 + (u >> 2);
        f32x4 acc[4][4];
        ACC_INIT(acc);
        const bf16* ga[4]; const bf16* gb[4];
#pragma unroll
        for (int c = 0; c < 4; c++) {
            int rt = c * 32 + wv * 8 + lrow;
            ga[c] = Xn  + (size_t)(mb * 128 + rt) * DIM + lch;
            gb[c] = W1t + (size_t)(nb * 128 + rt) * DIM + lch;
        }
        gemm_loop_db64<12>(ga, gb, As, Bs, acc);
        int cbase = nb * 128 + wn * 64 + (lane & 15);
        __syncthreads();
#pragma unroll
        for (int j = 0; j < 4; j++) {
            float bias = b1[cbase + j * 16];
#pragma unroll
            for (int i = 0; i < 4; i++)
#pragma unroll
                for (int r = 0; r < 4; r++) {
                    int lr = i * 16 + ((lane >> 4) << 2) + r;
                    int lc = j * 16 + (lane & 15);
                    cbuf[lr * 64 + lc] = (bf16)fast_gelu(acc[i][j][r] + bias);
                }
        }
        __syncthreads();
        store_tile(cbuf, lane, H + (size_t)(mb * 128 + wm * 64) * HID + nb * 128 + wn * 64, HID);
    } else {
        // ---- agemm1: 41 tiles x 12 N ----
        int t2 = bid - 768;
        int nb = t2 % 12, t = t2 / 12;
        int lvl = tile_meta[t];
        if (lvl < 0) return;
        f32x4 acc[4][4];
        ACC_INIT(acc);
        const bf16* ga[4]; const bf16* gb[4];
        const bf16* Bl = A1t + (size_t)lvl * HID2 * DIM;
#pragma unroll
        for (int c = 0; c < 4; c++) {
            int rt = c * 32 + wv * 8 + lrow;
            int rg = row_index[t * 128 + rt];
            ga[c] = (rg >= 0) ? (Xn + (size_t)rg * DIM + lch) : (zbuf + lch);
            gb[c] = Bl + (size_t)(nb * 128 + rt) * DIM + lch;
        }
        gemm_loop_db64<12>(ga, gb, As, Bs, acc);
        int cbase = nb * 128 + wn * 64 + (lane & 15);
        __syncthreads();
#pragma unroll
        for (int j = 0; j < 4; j++) {
            float bias = a1b[lvl * HID2 + cbase + j * 16];
#pragma unroll
            for (int i = 0; i < 4; i++)
#pragma unroll
                for (int r = 0; r < 4; r++) {
                    int lr = i * 16 + ((lane >> 4) << 2) + r;
                    int lc = j * 16 + (lane & 15);
                    cbuf[lr * 64 + lc] = (bf16)fmaxf(acc[i][j][r] + bias, 0.0f);
                }
        }
        __syncthreads();
        store_tile(cbuf, lane, HL + (size_t)(t * 128 + wm * 64) * HID2 + nb * 128 + wn * 64, HID2);
    }
}

// ---------------- mlp2: gemm2 splitK2 (KT=24) + agemm2 (KT=24) ----------------
__global__ __launch_bounds__(256) void mlp2_kernel(const bf16* __restrict__ H,
                                                   const bf16* __restrict__ W2t,
                                                   bf16* __restrict__ part,   // [2][ROWS*DIM]
                                                   const bf16* __restrict__ HL,
                                                   const bf16* __restrict__ A2t,
                                                   const float* __restrict__ a2b,
                                                   const int* __restrict__ row_index,
                                                   const int* __restrict__ tile_meta,
                                                   bf16* __restrict__ apart) { // [ROWS*DIM]
    __shared__ __align__(16) bf16 smem[32768];   // 64 KB
    bf16* As = smem;
    bf16* Bs = smem + 16384;
    int bid = xcd_swizzle(blockIdx.x, 384 + MAXTILES * 6);
    int tid = threadIdx.x;
    int lane = tid & 63, wv = tid >> 6, wm = wv >> 1, wn = wv & 1;
    int lrow = lane >> 3;
    int lch = ((lane & 7) ^ lrow) * 8;
    bf16* cbuf = smem + wv * 4096;
    f32x4 acc[4][4];
    ACC_INIT(acc);

    if (bid < 384) {
        // ---- gemm2: mb = bid/12 (12 consecutive blocks share the H chunk) ----
        int cc = bid % 12;
        int nb = cc >> 1, ks = cc & 1;
        int mb = bid / 12;
        const bf16* ga[4]; const bf16* gb[4];
#pragma unroll
        for (int c = 0; c < 4; c++) {
            int rt = c * 32 + wv * 8 + lrow;
            ga[c] = H   + (size_t)(mb * 128 + rt) * HID + ks * 1536 + lch;
            gb[c] = W2t + (size_t)(nb * 128 + rt) * HID + ks * 1536 + lch;
        }
        gemm_loop_db64<24>(ga, gb, As, Bs, acc);
        __syncthreads();
#pragma unroll
        for (int j = 0; j < 4; j++)
#pragma unroll
            for (int i = 0; i < 4; i++)
#pragma unroll
                for (int r = 0; r < 4; r++) {
                    int lr = i * 16 + ((lane >> 4) << 2) + r;
                    int lc = j * 16 + (lane & 15);
                    cbuf[lr * 64 + lc] = (bf16)acc[i][j][r];
                }
        __syncthreads();
        bf16* pk = part + (size_t)ks * ROWS * DIM;
        store_tile(cbuf, lane, pk + (size_t)(mb * 128 + wm * 64) * DIM + nb * 128 + wn * 64, DIM);
    } else {
        // ---- agemm2: 41 tiles x 6 N, full K=1536 ----
        int t2 = bid - 384;
        int nb = t2 % 6, t = t2 / 6;
        int lvl = tile_meta[t];
        if (lvl < 0) return;
        const bf16* ga[4]; const bf16* gb[4];
        const bf16* Bl = A2t + (size_t)lvl * DIM * HID2;
#pragma unroll
        for (int c = 0; c < 4; c++) {
            int rt = c * 32 + wv * 8 + lrow;
            ga[c] = HL + (size_t)(t * 128 + rt) * HID2 + lch;
            gb[c] = Bl + (size_t)(nb * 128 + rt) * HID2 + lch;
        }
        gemm_loop_db64<24>(ga, gb, As, Bs, acc);
        int cbase = nb * 128 + wn * 64 + (lane & 15);
        __syncthreads();
#pragma unroll
        for (int j = 0; j < 4; j++) {
            float bias = a2b[lvl * DIM + cbase + j * 16];
#pragma unroll
            for (int i = 0; i < 4; i++)
#pragma unroll
                for (int r = 0; r < 4; r++) {
                    int lr = i * 16 + ((lane >> 4) << 2) + r;
                    int lc = j * 16 + (lane & 15);
                    cbuf[lr * 64 + lc] = (bf16)(acc[i][j][r] + bias);
                }
        }
        __syncthreads();
        // gathered row store, still 128B-contiguous per row
        int colg = nb * 128 + wn * 64;
#pragma unroll
        for (int p = 0; p < 8; p++) {
            int lr = p * 8 + (lane >> 3);
            int chunk = (lane & 7) * 8;
            int rg = row_index[t * 128 + wm * 64 + lr];
            if (rg >= 0) {
                bf16x8 v = *(const bf16x8*)(cbuf + lr * 64 + chunk);
                *(bf16x8*)(apart + (size_t)rg * DIM + colg + chunk) = v;
            }
        }
    }
}

// ---------------- combine: out = (1-mix)*(p0+p1+b2) + mix*apart ----------------
__global__ __launch_bounds__(256) void combine_kernel(const bf16* __restrict__ part,
                                                      const bf16* __restrict__ apart,
                                                      const float* __restrict__ b2,
                                                      const float* __restrict__ mix,
                                                      float* __restrict__ out) {
    int i = blockIdx.x * 256 + threadIdx.x;
    int base = i * 4;
    int row = base / DIM;
    int c = base - row * DIM;
    float mx = mix[row & (SEQ - 1)];
    bf16x4 p0 = *(const bf16x4*)(part + base);
    bf16x4 p1 = *(const bf16x4*)(part + (size_t)ROWS * DIM + base);
    bf16x4 a0 = *(const bf16x4*)(apart + base);
    float4 o;
    float* po = &o.x;
#pragma unroll
    for (int k = 0; k < 4; k++) {
        float main_v = (float)p0[k] + (float)p1[k] + b2[c + k];
        po[k] = (1.0f - mx) * main_v + mx * (float)a0[k];
    }
    *(float4*)(out + base) = o;
}

// ---------------- launch ----------------
extern "C" void kernel_launch(void* const* d_in, const int* in_sizes, int n_in,
                              void* d_out, int out_size, void* d_ws, size_t ws_size,
                              hipStream_t stream) {
    const float* x    = (const float*)d_in[0];
    const int* levels = (const int*)d_in[1];
    const float* gamma= (const float*)d_in[2];
    const float* beta = (const float*)d_in[3];
    const float* W1   = (const float*)d_in[4];
    const float* b1   = (const float*)d_in[5];
    const float* W2   = (const float*)d_in[6];
    const float* b2   = (const float*)d_in[7];
    const float* A1   = (const float*)d_in[8];
    const float* a1b  = (const float*)d_in[9];
    const float* A2   = (const float*)d_in[10];
    const float* a2b  = (const float*)d_in[11];
    const float* lmw  = (const float*)d_in[12];
    float* out = (float*)d_out;

    char* p = (char*)d_ws;
    auto alloc = [&](size_t bytes) {
        char* r = p;
        p += (bytes + 255) & ~(size_t)255;
        return r;
    };
    bf16* Xn   = (bf16*)alloc((size_t)ROWS * DIM * 2);
    bf16* W1t  = (bf16*)alloc((size_t)HID * DIM * 2);
    bf16* W2t  = (bf16*)alloc((size_t)DIM * HID * 2);
    bf16* A1t  = (bf16*)alloc((size_t)NLEV * HID2 * DIM * 2);
    bf16* A2t  = (bf16*)alloc((size_t)NLEV * DIM * HID2 * 2);
    bf16* H    = (bf16*)alloc((size_t)ROWS * HID * 2);
    bf16* HL   = (bf16*)alloc((size_t)MAXPAD * HID2 * 2);
    bf16* part = (bf16*)alloc((size_t)2 * ROWS * DIM * 2);
    bf16* apart= (bf16*)alloc((size_t)ROWS * DIM * 2);
    float* mix = (float*)alloc(SEQ * 4);
    int* row_index = (int*)alloc(MAXPAD * 4);
    int* tile_meta = (int*)alloc(MAXTILES * 4);
    float* zbuf    = (float*)alloc(4096);   // 4 KB zero page

    // prep: routing(1) + LN4(1024) + W1t(576) + A1t(2592) + W2t(576) + A2t(2592)
    prep_kernel<<<dim3(1 + 1024 + 576 + 2592 + 576 + 2592), dim3(256), 0, stream>>>(
        x, levels, gamma, beta, W1, A1, W2, A2, lmw,
        Xn, W1t, A1t, W2t, A2t, mix, row_index, tile_meta, zbuf);

    // mlp1: pure GEMM — gemm1(768) + agemm1(492), BK=64, T1-swizzled
    mlp1_kernel<<<dim3(768 + 492), dim3(256), 0, stream>>>(
        Xn, W1t, b1, H, A1t, a1b, row_index, tile_meta, (const bf16*)zbuf, HL);

    // mlp2: gemm2 splitK2 (384, KT=24) + agemm2 (246, KT=24), BK=64, T1-swizzled
    mlp2_kernel<<<dim3(384 + MAXTILES * 6), dim3(256), 0, stream>>>(
        H, W2t, part, HL, A2t, a2b, row_index, tile_meta, apart);

    combine_kernel<<<dim3(ROWS * DIM / 1024), dim3(256), 0, stream>>>(
        part, apart, b2, mix, out);
}

// Round 9
// 259.235 us; speedup vs baseline: 1.2035x; 1.0150x over previous
//
#include <hip/hip_runtime.h>
#include <hip/hip_bf16.h>
#include <math.h>

typedef __bf16 bf16;
typedef __bf16 bf16x4 __attribute__((ext_vector_type(4)));
typedef __bf16 bf16x8 __attribute__((ext_vector_type(8)));
typedef float f32x4 __attribute__((ext_vector_type(4)));

#define DIM 768
#define HID 3072
#define HID2 1536
#define NLEV 9
#define SEQ 2048
#define ROWS 4096            // BATCH*SEQ
#define MAXPAD 5248          // ROWS + NLEV*128 (rounded)
#define MAXTILES 41          // MAXPAD/128

// ---------------- async global->LDS 16B ----------------
__device__ __forceinline__ void gld16(const void* g, void* l) {
    __builtin_amdgcn_global_load_lds(
        (const __attribute__((address_space(1))) void*)g,
        (__attribute__((address_space(3))) void*)l, 16, 0, 0);
}

// fast tanh-GELU: max |err| vs exact-erf gelu ~5e-4
__device__ __forceinline__ float fast_gelu(float v) {
    float v2 = v * v;
    float twou = v * (1.59576912f + 0.071354816f * v2);
    float t = __expf(twou);
    return v * t / (t + 1.0f);
}

// T1: XCD-bijective swizzle (m204). Dispatch slot s -> work id, so each XCD's
// slots (s%8 round-robin) receive a CONTIGUOUS work chunk (L2 locality).
__device__ __forceinline__ int xcd_swizzle(int s, int nwg) {
    int q = nwg >> 3, r = nwg & 7;
    int x = s & 7, i = s >> 3;
    return (x < r ? x * (q + 1) : r * (q + 1) + (x - r) * q) + i;
}

// ================= PREP bodies =================

// LayerNorm, one WAVE per row (no barriers, no LDS). Block = 4 waves = 4 rows.
__device__ __forceinline__ void ln4_body(int blk,
                                         const float* __restrict__ x,
                                         const float* __restrict__ gamma,
                                         const float* __restrict__ beta,
                                         bf16* __restrict__ xn) {
    int tid = threadIdx.x;
    int wv = tid >> 6, ln = tid & 63;
    int row = blk * 4 + wv;
    const float* xr = x + (size_t)row * DIM;
    int c = ln * 4;
    float4 v0 = *(const float4*)(xr + c);
    float4 v1 = *(const float4*)(xr + c + 256);
    float4 v2 = *(const float4*)(xr + c + 512);
    float s = v0.x + v0.y + v0.z + v0.w
            + v1.x + v1.y + v1.z + v1.w
            + v2.x + v2.y + v2.z + v2.w;
    float q = v0.x * v0.x + v0.y * v0.y + v0.z * v0.z + v0.w * v0.w
            + v1.x * v1.x + v1.y * v1.y + v1.z * v1.z + v1.w * v1.w
            + v2.x * v2.x + v2.y * v2.y + v2.z * v2.z + v2.w * v2.w;
#pragma unroll
    for (int off = 32; off; off >>= 1) {
        s += __shfl_xor(s, off, 64);
        q += __shfl_xor(q, off, 64);
    }
    float m = s * (1.0f / DIM);
    float r = rsqrtf(q * (1.0f / DIM) - m * m + 1e-5f);
    bf16* xo = xn + (size_t)row * DIM;
#pragma unroll
    for (int p = 0; p < 3; p++) {
        int cc = c + p * 256;
        float4 v = (p == 0) ? v0 : (p == 1) ? v1 : v2;
        float4 g = *(const float4*)(gamma + cc);
        float4 b = *(const float4*)(beta + cc);
        bf16x4 o;
        o[0] = (bf16)((v.x - m) * r * g.x + b.x);
        o[1] = (bf16)((v.y - m) * r * g.y + b.y);
        o[2] = (bf16)((v.z - m) * r * g.z + b.z);
        o[3] = (bf16)((v.w - m) * r * g.w + b.w);
        *(bf16x4*)(xo + cc) = o;
    }
}

// 64x64 tile transpose: fp32 [R][C] -> bf16 [C][R]. bf16 LDS [64][68] (8.4 KB).
__device__ __forceinline__ void transpose_body64(bf16* sm,
                                                 const float* __restrict__ inb,
                                                 bf16* __restrict__ outb,
                                                 int R, int C, int bx, int by) {
    int tid = threadIdx.x;
    int ty = tid >> 4;
    int tx4 = (tid & 15) * 4;
#pragma unroll
    for (int p = 0; p < 4; p++) {
        int rloc = p * 16 + ty;
        int row = by * 64 + rloc;
        float4 v = *(const float4*)(inb + (size_t)row * C + bx * 64 + tx4);
        bf16x4 o;
        o[0] = (bf16)v.x; o[1] = (bf16)v.y; o[2] = (bf16)v.z; o[3] = (bf16)v.w;
        *(bf16x4*)(sm + rloc * 68 + tx4) = o;
    }
    __syncthreads();
    int ch = tid & 7;
    int ocb = tid >> 3;
#pragma unroll
    for (int p = 0; p < 2; p++) {
        int oc = p * 32 + ocb;
        bf16x8 tmp;
#pragma unroll
        for (int k = 0; k < 8; k++) tmp[k] = sm[(ch * 8 + k) * 68 + oc];
        *(bf16x8*)(outb + (size_t)(bx * 64 + oc) * R + by * 64 + ch * 8) = tmp;
    }
}

__device__ __forceinline__ void routing_body(float* sm,
                                             const int* __restrict__ levels_info,
                                             const float* __restrict__ lmw,
                                             float* __restrict__ mix,
                                             int* __restrict__ row_index,
                                             int* __restrict__ tile_meta,
                                             float* __restrict__ zbuf) {
    int* cnt = (int*)sm;
    int* cur = cnt + NLEV;
    int* off = cur + NLEV;
    float* mixv = (float*)(off + NLEV);
    int tid = threadIdx.x;
    if (tid < NLEV) { cnt[tid] = 0; cur[tid] = 0; }
    __syncthreads();
    for (int s = tid; s < SEQ; s += 256) {
        int d = levels_info[s * 4];
        d = d < 0 ? 0 : (d > 8 ? 8 : d);
        atomicAdd(&cnt[d], 1);
    }
    for (int i = tid; i < MAXPAD; i += 256) row_index[i] = -1;
    for (int i = tid; i < 1024; i += 256) zbuf[i] = 0.0f;   // 4 KB zero page
    __syncthreads();
    if (tid == 0) {
        float mx = lmw[0];
        for (int l = 1; l < NLEV; l++) mx = fmaxf(mx, lmw[l]);
        float denom = 0.f;
        for (int l = 0; l < NLEV; l++) denom += (float)cnt[l] * expf(lmw[l] - mx);
        float inv = 1.0f / denom;
        int running = 0, t = 0;
        for (int l = 0; l < NLEV; l++) {
            mixv[l] = expf(lmw[l] - mx) * inv;
            off[l] = running;
            int seg = (2 * cnt[l] + 127) & ~127;
            for (int k = 0; k < seg / 128; k++) tile_meta[t++] = l;
            running += seg;
        }
        for (; t < MAXTILES; t++) tile_meta[t] = -1;
    }
    __syncthreads();
    for (int s = tid; s < SEQ; s += 256) {
        int d = levels_info[s * 4];
        d = d < 0 ? 0 : (d > 8 ? 8 : d);
        int p = atomicAdd(&cur[d], 2);
        row_index[off[d] + p]     = s;
        row_index[off[d] + p + 1] = s + SEQ;
        mix[s] = mixv[d];
    }
}

// ---------------- prep: routing + LN + ALL weight transposes ----------------
__global__ __launch_bounds__(256) void prep_kernel(const float* __restrict__ x,
                                                   const int* __restrict__ levels_info,
                                                   const float* __restrict__ gamma,
                                                   const float* __restrict__ beta,
                                                   const float* __restrict__ W1,
                                                   const float* __restrict__ A1,
                                                   const float* __restrict__ W2,
                                                   const float* __restrict__ A2,
                                                   const float* __restrict__ lmw,
                                                   bf16* __restrict__ Xn,
                                                   bf16* __restrict__ W1t,
                                                   bf16* __restrict__ A1t,
                                                   bf16* __restrict__ W2t,
                                                   bf16* __restrict__ A2t,
                                                   float* __restrict__ mix,
                                                   int* __restrict__ row_index,
                                                   int* __restrict__ tile_meta,
                                                   float* __restrict__ zbuf) {
    __shared__ __align__(16) bf16 tsm[64 * 68];
    int b = blockIdx.x;
    if (b == 0) { routing_body((float*)tsm, levels_info, lmw, mix, row_index, tile_meta, zbuf); return; }
    b -= 1;
    if (b < 1024) { ln4_body(b, x, gamma, beta, Xn); return; }
    b -= 1024;
    if (b < 576) {
        transpose_body64(tsm, W1, W1t, DIM, HID, b % 48, b / 48);
        return;
    }
    b -= 576;
    if (b < 2592) {
        int bz = b / 288, r = b % 288;
        transpose_body64(tsm, A1 + (size_t)bz * DIM * HID2, A1t + (size_t)bz * DIM * HID2,
                         DIM, HID2, r % 24, r / 24);
        return;
    }
    b -= 2592;
    if (b < 576) {
        transpose_body64(tsm, W2, W2t, HID, DIM, b % 12, b / 12);
        return;
    }
    b -= 576;
    {
        int bz = b / 288, r = b % 288;
        transpose_body64(tsm, A2 + (size_t)bz * HID2 * DIM, A2t + (size_t)bz * HID2 * DIM,
                         HID2, DIM, r % 12, r / 12);
    }
}

// ---------------- BK=64 double-buffered GEMM K-loop ----------------
// LDS: As = 2 x 8192 elems (16 KB each), Bs same -> 64 KB total.
// Producer: gld16 writes LINEAR LDS (wave-uniform base + lane*16B), 8 rows x
// 128B per call; the XOR swizzle (chunk ^= row&7) is applied on the per-lane
// GLOBAL source address (m173 pattern). Each 8-lane group covers one aligned
// 128B row window -> full-width HBM requests.
// Consumer: ds_read_b128 at chunk' = ((k32<<2)|kc) ^ (lane&7) -> <=2-way bank
// conflicts (free). Half the barriers/vmcnt-drains of the BK=32 loop.
template<int KT>   // KT = K/64
__device__ __forceinline__ void gemm_loop_db64(const bf16* (&ga)[4], const bf16* (&gb)[4],
                                               bf16* As, bf16* Bs,
                                               f32x4 (&acc)[4][4]) {
    int tid = threadIdx.x;
    int wv = tid >> 6;
    int lane = tid & 63;
    int wm = wv >> 1, wn = wv & 1;
    int r = lane & 15;
    int ch0 = ((lane >> 4) ^ (lane & 7)) * 8;          // swizzled k-chunk, k32=0
    int aoff = (wm * 64 + r) * 64 + ch0;
    int boff = (wn * 64 + r) * 64 + ch0;
#pragma unroll
    for (int c = 0; c < 4; c++) {
        gld16(ga[c], As + (c * 32 + wv * 8) * 64);
        gld16(gb[c], Bs + (c * 32 + wv * 8) * 64);
        ga[c] += 64; gb[c] += 64;
    }
#pragma unroll
    for (int kt = 0; kt < KT; ++kt) {
        __syncthreads();
        const int cur = (kt & 1) << 13;
        const int nxt = cur ^ 8192;
        if (kt + 1 < KT) {
#pragma unroll
            for (int c = 0; c < 4; c++) {
                gld16(ga[c], As + nxt + (c * 32 + wv * 8) * 64);
                gld16(gb[c], Bs + nxt + (c * 32 + wv * 8) * 64);
                ga[c] += 64; gb[c] += 64;
            }
        }
#pragma unroll
        for (int k32 = 0; k32 < 2; k32++) {
            const int kx = k32 << 5;                   // XOR 32 elems = k-chunk bit2
            bf16x8 af[4], bfr[4];
#pragma unroll
            for (int i = 0; i < 4; i++) af[i] = *(const bf16x8*)(As + cur + ((aoff + i * 1024) ^ kx));
#pragma unroll
            for (int j = 0; j < 4; j++) bfr[j] = *(const bf16x8*)(Bs + cur + ((boff + j * 1024) ^ kx));
#pragma unroll
            for (int i = 0; i < 4; i++)
#pragma unroll
                for (int j = 0; j < 4; j++)
                    acc[i][j] = __builtin_amdgcn_mfma_f32_16x16x32_bf16(af[i], bfr[j], acc[i][j], 0, 0, 0);
        }
    }
}

#define ACC_INIT(acc) \
    _Pragma("unroll") for (int i = 0; i < 4; i++) \
    _Pragma("unroll") for (int j = 0; j < 4; j++) acc[i][j] = (f32x4){0.f, 0.f, 0.f, 0.f};

// contiguous 128B-row store of a wave's 64x64 bf16 tile staged in cbuf
__device__ __forceinline__ void store_tile(const bf16* cbuf, int lane,
                                           bf16* gptr, int ldg) {
#pragma unroll
    for (int p = 0; p < 8; p++) {
        int lrow = p * 8 + (lane >> 3);
        int chunk = (lane & 7) * 8;
        bf16x8 v = *(const bf16x8*)(cbuf + lrow * 64 + chunk);
        *(bf16x8*)(gptr + (size_t)lrow * ldg + chunk) = v;
    }
}

// ---------------- mlp1: PURE GEMM — gemm1(768, clustered) + agemm1(492) ----------------
__global__ __launch_bounds__(256) void mlp1_kernel(const bf16* __restrict__ Xn,
                                                   const bf16* __restrict__ W1t,
                                                   const float* __restrict__ b1,
                                                   bf16* __restrict__ H,
                                                   const bf16* __restrict__ A1t,
                                                   const float* __restrict__ a1b,
                                                   const int* __restrict__ row_index,
                                                   const int* __restrict__ tile_meta,
                                                   const bf16* __restrict__ zbuf,
                                                   bf16* __restrict__ HL) {
    __shared__ __align__(16) bf16 smem[32768];   // 64 KB
    bf16* As = smem;
    bf16* Bs = smem + 16384;
    int bid = xcd_swizzle(blockIdx.x, 1260);
    int tid = threadIdx.x;
    int lane = tid & 63, wv = tid >> 6, wm = wv >> 1, wn = wv & 1;
    int lrow = lane >> 3;                       // 0..7 row within 8-row group
    int lch = ((lane & 7) ^ lrow) * 8;          // pre-swizzled global chunk
    bf16* cbuf = smem + wv * 4096;

    if (bid < 768) {
        // ---- gemm1: 24 clusters of 4nb x 8mb (2.4 MB working set, XCD-L2-fit) ----
        int s = bid >> 5, u = bid & 31;
        int nb = (s % 6) * 4 + (u & 3);
        int mb = (s / 6) * 8 + (u >> 2);
        f32x4 acc[4][4];
        ACC_INIT(acc);
        const bf16* ga[4]; const bf16* gb[4];
#pragma unroll
        for (int c = 0; c < 4; c++) {
            int rt = c * 32 + wv * 8 + lrow;
            ga[c] = Xn  + (size_t)(mb * 128 + rt) * DIM + lch;
            gb[c] = W1t + (size_t)(nb * 128 + rt) * DIM + lch;
        }
        gemm_loop_db64<12>(ga, gb, As, Bs, acc);
        int cbase = nb * 128 + wn * 64 + (lane & 15);
        __syncthreads();
#pragma unroll
        for (int j = 0; j < 4; j++) {
            float bias = b1[cbase + j * 16];
#pragma unroll
            for (int i = 0; i < 4; i++)
#pragma unroll
                for (int r = 0; r < 4; r++) {
                    int lr = i * 16 + ((lane >> 4) << 2) + r;
                    int lc = j * 16 + (lane & 15);
                    cbuf[lr * 64 + lc] = (bf16)fast_gelu(acc[i][j][r] + bias);
                }
        }
        __syncthreads();
        store_tile(cbuf, lane, H + (size_t)(mb * 128 + wm * 64) * HID + nb * 128 + wn * 64, HID);
    } else {
        // ---- agemm1: 41 tiles x 12 N ----
        int t2 = bid - 768;
        int nb = t2 % 12, t = t2 / 12;
        int lvl = tile_meta[t];
        if (lvl < 0) return;
        f32x4 acc[4][4];
        ACC_INIT(acc);
        const bf16* ga[4]; const bf16* gb[4];
        const bf16* Bl = A1t + (size_t)lvl * HID2 * DIM;
#pragma unroll
        for (int c = 0; c < 4; c++) {
            int rt = c * 32 + wv * 8 + lrow;
            int rg = row_index[t * 128 + rt];
            ga[c] = (rg >= 0) ? (Xn + (size_t)rg * DIM + lch) : (zbuf + lch);
            gb[c] = Bl + (size_t)(nb * 128 + rt) * DIM + lch;
        }
        gemm_loop_db64<12>(ga, gb, As, Bs, acc);
        int cbase = nb * 128 + wn * 64 + (lane & 15);
        __syncthreads();
#pragma unroll
        for (int j = 0; j < 4; j++) {
            float bias = a1b[lvl * HID2 + cbase + j * 16];
#pragma unroll
            for (int i = 0; i < 4; i++)
#pragma unroll
                for (int r = 0; r < 4; r++) {
                    int lr = i * 16 + ((lane >> 4) << 2) + r;
                    int lc = j * 16 + (lane & 15);
                    cbuf[lr * 64 + lc] = (bf16)fmaxf(acc[i][j][r] + bias, 0.0f);
                }
        }
        __syncthreads();
        store_tile(cbuf, lane, HL + (size_t)(t * 128 + wm * 64) * HID2 + nb * 128 + wn * 64, HID2);
    }
}

// ---------------- mlp2: gemm2 splitK2 (KT=24) + agemm2 (KT=24) ----------------
__global__ __launch_bounds__(256) void mlp2_kernel(const bf16* __restrict__ H,
                                                   const bf16* __restrict__ W2t,
                                                   bf16* __restrict__ part,   // [2][ROWS*DIM]
                                                   const bf16* __restrict__ HL,
                                                   const bf16* __restrict__ A2t,
                                                   const float* __restrict__ a2b,
                                                   const int* __restrict__ row_index,
                                                   const int* __restrict__ tile_meta,
                                                   bf16* __restrict__ apart) { // [ROWS*DIM]
    __shared__ __align__(16) bf16 smem[32768];   // 64 KB
    bf16* As = smem;
    bf16* Bs = smem + 16384;
    int bid = xcd_swizzle(blockIdx.x, 384 + MAXTILES * 6);
    int tid = threadIdx.x;
    int lane = tid & 63, wv = tid >> 6, wm = wv >> 1, wn = wv & 1;
    int lrow = lane >> 3;
    int lch = ((lane & 7) ^ lrow) * 8;
    bf16* cbuf = smem + wv * 4096;
    f32x4 acc[4][4];
    ACC_INIT(acc);

    if (bid < 384) {
        // ---- gemm2: mb = bid/12 (12 consecutive blocks share the H chunk) ----
        int cc = bid % 12;
        int nb = cc >> 1, ks = cc & 1;
        int mb = bid / 12;
        const bf16* ga[4]; const bf16* gb[4];
#pragma unroll
        for (int c = 0; c < 4; c++) {
            int rt = c * 32 + wv * 8 + lrow;
            ga[c] = H   + (size_t)(mb * 128 + rt) * HID + ks * 1536 + lch;
            gb[c] = W2t + (size_t)(nb * 128 + rt) * HID + ks * 1536 + lch;
        }
        gemm_loop_db64<24>(ga, gb, As, Bs, acc);
        __syncthreads();
#pragma unroll
        for (int j = 0; j < 4; j++)
#pragma unroll
            for (int i = 0; i < 4; i++)
#pragma unroll
                for (int r = 0; r < 4; r++) {
                    int lr = i * 16 + ((lane >> 4) << 2) + r;
                    int lc = j * 16 + (lane & 15);
                    cbuf[lr * 64 + lc] = (bf16)acc[i][j][r];
                }
        __syncthreads();
        bf16* pk = part + (size_t)ks * ROWS * DIM;
        store_tile(cbuf, lane, pk + (size_t)(mb * 128 + wm * 64) * DIM + nb * 128 + wn * 64, DIM);
    } else {
        // ---- agemm2: 41 tiles x 6 N, full K=1536 ----
        int t2 = bid - 384;
        int nb = t2 % 6, t = t2 / 6;
        int lvl = tile_meta[t];
        if (lvl < 0) return;
        const bf16* ga[4]; const bf16* gb[4];
        const bf16* Bl = A2t + (size_t)lvl * DIM * HID2;
#pragma unroll
        for (int c = 0; c < 4; c++) {
            int rt = c * 32 + wv * 8 + lrow;
            ga[c] = HL + (size_t)(t * 128 + rt) * HID2 + lch;
            gb[c] = Bl + (size_t)(nb * 128 + rt) * HID2 + lch;
        }
        gemm_loop_db64<24>(ga, gb, As, Bs, acc);
        int cbase = nb * 128 + wn * 64 + (lane & 15);
        __syncthreads();
#pragma unroll
        for (int j = 0; j < 4; j++) {
            float bias = a2b[lvl * DIM + cbase + j * 16];
#pragma unroll
            for (int i = 0; i < 4; i++)
#pragma unroll
                for (int r = 0; r < 4; r++) {
                    int lr = i * 16 + ((lane >> 4) << 2) + r;
                    int lc = j * 16 + (lane & 15);
                    cbuf[lr * 64 + lc] = (bf16)(acc[i][j][r] + bias);
                }
        }
        __syncthreads();
        // gathered row store, still 128B-contiguous per row
        int colg = nb * 128 + wn * 64;
#pragma unroll
        for (int p = 0; p < 8; p++) {
            int lr = p * 8 + (lane >> 3);
            int chunk = (lane & 7) * 8;
            int rg = row_index[t * 128 + wm * 64 + lr];
            if (rg >= 0) {
                bf16x8 v = *(const bf16x8*)(cbuf + lr * 64 + chunk);
                *(bf16x8*)(apart + (size_t)rg * DIM + colg + chunk) = v;
            }
        }
    }
}

// ---------------- combine: out = (1-mix)*(p0+p1+b2) + mix*apart ----------------
__global__ __launch_bounds__(256) void combine_kernel(const bf16* __restrict__ part,
                                                      const bf16* __restrict__ apart,
                                                      const float* __restrict__ b2,
                                                      const float* __restrict__ mix,
                                                      float* __restrict__ out) {
    int i = blockIdx.x * 256 + threadIdx.x;
    int base = i * 4;
    int row = base / DIM;
    int c = base - row * DIM;
    float mx = mix[row & (SEQ - 1)];
    bf16x4 p0 = *(const bf16x4*)(part + base);
    bf16x4 p1 = *(const bf16x4*)(part + (size_t)ROWS * DIM + base);
    bf16x4 a0 = *(const bf16x4*)(apart + base);
    float4 o;
    float* po = &o.x;
#pragma unroll
    for (int k = 0; k < 4; k++) {
        float main_v = (float)p0[k] + (float)p1[k] + b2[c + k];
        po[k] = (1.0f - mx) * main_v + mx * (float)a0[k];
    }
    *(float4*)(out + base) = o;
}

// ---------------- launch ----------------
extern "C" void kernel_launch(void* const* d_in, const int* in_sizes, int n_in,
                              void* d_out, int out_size, void* d_ws, size_t ws_size,
                              hipStream_t stream) {
    const float* x    = (const float*)d_in[0];
    const int* levels = (const int*)d_in[1];
    const float* gamma= (const float*)d_in[2];
    const float* beta = (const float*)d_in[3];
    const float* W1   = (const float*)d_in[4];
    const float* b1   = (const float*)d_in[5];
    const float* W2   = (const float*)d_in[6];
    const float* b2   = (const float*)d_in[7];
    const float* A1   = (const float*)d_in[8];
    const float* a1b  = (const float*)d_in[9];
    const float* A2   = (const float*)d_in[10];
    const float* a2b  = (const float*)d_in[11];
    const float* lmw  = (const float*)d_in[12];
    float* out = (float*)d_out;

    char* p = (char*)d_ws;
    auto alloc = [&](size_t bytes) {
        char* r = p;
        p += (bytes + 255) & ~(size_t)255;
        return r;
    };
    bf16* Xn   = (bf16*)alloc((size_t)ROWS * DIM * 2);
    bf16* W1t  = (bf16*)alloc((size_t)HID * DIM * 2);
    bf16* W2t  = (bf16*)alloc((size_t)DIM * HID * 2);
    bf16* A1t  = (bf16*)alloc((size_t)NLEV * HID2 * DIM * 2);
    bf16* A2t  = (bf16*)alloc((size_t)NLEV * DIM * HID2 * 2);
    bf16* H    = (bf16*)alloc((size_t)ROWS * HID * 2);
    bf16* HL   = (bf16*)alloc((size_t)MAXPAD * HID2 * 2);
    bf16* part = (bf16*)alloc((size_t)2 * ROWS * DIM * 2);
    bf16* apart= (bf16*)alloc((size_t)ROWS * DIM * 2);
    float* mix = (float*)alloc(SEQ * 4);
    int* row_index = (int*)alloc(MAXPAD * 4);
    int* tile_meta = (int*)alloc(MAXTILES * 4);
    float* zbuf    = (float*)alloc(4096);   // 4 KB zero page

    // prep: routing(1) + LN4(1024) + W1t(576) + A1t(2592) + W2t(576) + A2t(2592)
    prep_kernel<<<dim3(1 + 1024 + 576 + 2592 + 576 + 2592), dim3(256), 0, stream>>>(
        x, levels, gamma, beta, W1, A1, W2, A2, lmw,
        Xn, W1t, A1t, W2t, A2t, mix, row_index, tile_meta, zbuf);

    // mlp1: pure GEMM — gemm1(768) + agemm1(492), BK=64, T1-swizzled
    mlp1_kernel<<<dim3(768 + 492), dim3(256), 0, stream>>>(
        Xn, W1t, b1, H, A1t, a1b, row_index, tile_meta, (const bf16*)zbuf, HL);

    // mlp2: gemm2 splitK2 (384, KT=24) + agemm2 (246, KT=24), BK=64, T1-swizzled
    mlp2_kernel<<<dim3(384 + MAXTILES * 6), dim3(256), 0, stream>>>(
        H, W2t, part, HL, A2t, a2b, row_index, tile_meta, apart);

    combine_kernel<<<dim3(ROWS * DIM / 1024), dim3(256), 0, stream>>>(
        part, apart, b2, mix, out);
}